// Round 3
// baseline (278.418 us; speedup 1.0000x reference)
//
#include <hip/hip_runtime.h>
#include <hip/hip_bf16.h>

// B=4, T=1024, E=1024, ATT=64, NH=16, AH=1024. M = B*T = 4096, K = N = 1024.
// Pipeline: cast x->bf16; transpose+cast W{q,k,v,o} -> [N][K] bf16;
//           fused QKV MFMA GEMM (128x128, global_load_lds, K-slab pre-scaled
//           by 0.125*log2e); register-path MFMA flash attention (S^T trick,
//           HW v_exp_f32); O-proj GEMM (64x128 -> 512 blocks).

typedef __bf16 bf16_t;
typedef bf16_t bf16x8 __attribute__((ext_vector_type(8)));
typedef short  s16x4 __attribute__((ext_vector_type(4)));
typedef float  f32x4 __attribute__((ext_vector_type(4)));

#define SCALE_LOG2E 0.18033688011112042f  /* 0.125 * log2(e) */

__device__ __forceinline__ void async16(const bf16_t* g, void* l) {
    __builtin_amdgcn_global_load_lds(
        (const __attribute__((address_space(1))) unsigned int*)g,
        (__attribute__((address_space(3))) unsigned int*)l,
        16, 0, 0);
}

// ---------- cast fp32 -> bf16, 8 elems/thread ----------
__global__ __launch_bounds__(256) void cast_f32_bf16(
    const float* __restrict__ in, bf16_t* __restrict__ out, int n8)
{
    int i = blockIdx.x * 256 + threadIdx.x;
    if (i >= n8) return;
    const float4* p = (const float4*)in + (size_t)i * 2;
    float4 a = p[0], b = p[1];
    bf16x8 o;
    o[0] = (bf16_t)a.x; o[1] = (bf16_t)a.y; o[2] = (bf16_t)a.z; o[3] = (bf16_t)a.w;
    o[4] = (bf16_t)b.x; o[5] = (bf16_t)b.y; o[6] = (bf16_t)b.z; o[7] = (bf16_t)b.w;
    *((bf16x8*)out + i) = o;
}

// ---------- transpose + cast: W [1024][1024] fp32 [K][N] -> [N][K] bf16 ----------
__global__ __launch_bounds__(256) void transpose_cast(
    const float* __restrict__ W0, const float* __restrict__ W1,
    const float* __restrict__ W2, const float* __restrict__ W3,
    bf16_t* __restrict__ out)
{
    __shared__ float st[32][33];
    const float* W = (blockIdx.z == 0) ? W0 : (blockIdx.z == 1) ? W1
                   : (blockIdx.z == 2) ? W2 : W3;
    bf16_t* o = out + (size_t)blockIdx.z * 1024 * 1024;
    const int n0 = blockIdx.x * 32, k0 = blockIdx.y * 32;
    const int t = threadIdx.x;
    const int r = t >> 3, c4 = (t & 7) * 4;
    float4 v = *(const float4*)(W + (size_t)(k0 + r) * 1024 + n0 + c4);
    st[r][c4 + 0] = v.x; st[r][c4 + 1] = v.y; st[r][c4 + 2] = v.z; st[r][c4 + 3] = v.w;
    __syncthreads();
    bf16_t tmp[4] __attribute__((aligned(8)));
    #pragma unroll
    for (int i = 0; i < 4; ++i) tmp[i] = (bf16_t)st[c4 + i][r];
    *(uint2*)(o + (size_t)(n0 + r) * 1024 + k0 + c4) = *(const uint2*)tmp;
}

// ---------- MFMA GEMM: C = A[M,1024] @ Bt[N,1024]^T + bias ----------
template<bool FUSED, int MT>
__global__ __launch_bounds__(256, 3) void gemm_glds(
    const bf16_t* __restrict__ A, const bf16_t* __restrict__ Bt,
    const float* __restrict__ b0, const float* __restrict__ b1,
    const float* __restrict__ b2,
    bf16_t* __restrict__ Qo, bf16_t* __restrict__ Ko, bf16_t* __restrict__ Vo,
    float* __restrict__ Fo)
{
    const int K = 1024;
    __shared__ __align__(16) bf16_t As[MT * 32];
    __shared__ __align__(16) bf16_t Bs[128 * 32];

    constexpr int NTPW = (MT == 128) ? 4 : 2;
    constexpr int JA   = MT / 64;

    const int tid  = threadIdx.x;
    const int wave = tid >> 6;
    const int lane = tid & 63;
    const int quad = lane >> 4;
    const int l16  = lane & 15;
    const int m0 = blockIdx.y * MT;
    const int n0 = blockIdx.x * 128;
    const int wm = (MT == 128) ? (wave >> 1) * 64 : 0;
    const int wn = (MT == 128) ? (wave & 1) * 64 : wave * 32;

    int goffA[JA], goffB[2];
    #pragma unroll
    for (int j = 0; j < JA; ++j) {
        const int row = j * 64 + (tid >> 2);
        const int cl  = (tid & 3) ^ ((row >> 1) & 3);
        goffA[j] = (m0 + row) * K + cl * 8;
    }
    #pragma unroll
    for (int j = 0; j < 2; ++j) {
        const int row = j * 64 + (tid >> 2);
        const int cl  = (tid & 3) ^ ((row >> 1) & 3);
        goffB[j] = (n0 + row) * K + cl * 8;
    }
    const int ldsoff = wave * 1024;

    f32x4 acc[4][NTPW] = {};
    const int sw = (l16 >> 1) & 3;

    for (int k0 = 0; k0 < K; k0 += 32) {
        #pragma unroll
        for (int j = 0; j < JA; ++j)
            async16(A + goffA[j] + k0, (char*)As + j * 4096 + ldsoff);
        #pragma unroll
        for (int j = 0; j < 2; ++j)
            async16(Bt + goffB[j] + k0, (char*)Bs + j * 4096 + ldsoff);
        __syncthreads();

        bf16x8 af[4], bfr[NTPW];
        #pragma unroll
        for (int mt = 0; mt < 4; ++mt)
            af[mt] = *(const bf16x8*)(&As[(wm + mt * 16 + l16) * 32 + (quad ^ sw) * 8]);
        #pragma unroll
        for (int nt = 0; nt < NTPW; ++nt)
            bfr[nt] = *(const bf16x8*)(&Bs[(wn + nt * 16 + l16) * 32 + (quad ^ sw) * 8]);
        #pragma unroll
        for (int mt = 0; mt < 4; ++mt)
            #pragma unroll
            for (int nt = 0; nt < NTPW; ++nt)
                acc[mt][nt] = __builtin_amdgcn_mfma_f32_16x16x32_bf16(
                    af[mt], bfr[nt], acc[mt][nt], 0, 0, 0);
        __syncthreads();
    }

    if (FUSED) {
        const int sel = n0 >> 10;
        const float* bias = (sel == 0) ? b0 : (sel == 1) ? b1 : b2;
        bf16_t* Cout      = (sel == 0) ? Qo : (sel == 1) ? Ko : Vo;
        const float scl   = (sel == 1) ? SCALE_LOG2E : 1.0f;
        const int nb = n0 & 1023;
        #pragma unroll
        for (int nt = 0; nt < NTPW; ++nt) {
            const int n = nb + wn + nt * 16 + l16;
            const float bb = bias[n];
            #pragma unroll
            for (int mt = 0; mt < 4; ++mt)
                #pragma unroll
                for (int i = 0; i < 4; ++i) {
                    const int m = m0 + wm + mt * 16 + quad * 4 + i;
                    Cout[(size_t)m * 1024 + n] = (bf16_t)((acc[mt][nt][i] + bb) * scl);
                }
        }
    } else {
        #pragma unroll
        for (int nt = 0; nt < NTPW; ++nt) {
            const int n = n0 + wn + nt * 16 + l16;
            const float bb = b0[n];
            #pragma unroll
            for (int mt = 0; mt < 4; ++mt)
                #pragma unroll
                for (int i = 0; i < 4; ++i) {
                    const int m = m0 + wm + mt * 16 + quad * 4 + i;
                    Fo[(size_t)m * 1024 + n] = acc[mt][nt][i] + bb;
                }
        }
    }
}

// ---------- MFMA flash attention, register-path P, HW exp ----------
// Grid 2048: (head hd = bx>>3, q-chunk qc = bx&7). 256 thr = 4 waves, wave
// owns 32 q rows (2 q-subs of 16). launch_bounds(256,8) -> 8 blocks/CU =
// 32 waves/CU resident (round 0 was grid-limited at 16 waves/CU).
// Compute core is VERBATIM round-0 (proven on HW at 191.6us): K pre-scaled
// by 0.125*log2e; S^T = K.Q^T (swap operands) via mfma_f32_16x16x32_bf16
// with quads 2-3 zeroed (d=16); C-layout of S^T gives lane q=l16,
// keys=quad*4+i == B-operand layout of v_mfma_f32_16x16x16bf16_1k.
// p = exp2(s) packed in-register (+0x8000 round, 2 v_perm) feeds
// Z^T = V^T.P^T and l = 1.P^T directly. exp via __builtin_amdgcn_exp2f =
// bare v_exp_f32 (plain exp2f lowers to the libm __ocml_exp2_f32
// expansion, ~15 VALU/score). j-loop fully unrolled so double-buffer regs
// stay in VGPRs (runtime-indexed reg arrays spill to scratch).
// NOTE rounds 1-2 (NaN, reverted): QK via 16x16x16bf16_1k + inline-asm
// v_cvt_pk_bf16_f32 packing. Suspect TRANS(v_exp)->inline-asm hazard; do
// not reintroduce without isolating.
__global__ __launch_bounds__(256, 8) void attn_kernel(
    const bf16_t* __restrict__ Q, const bf16_t* __restrict__ K,
    const bf16_t* __restrict__ V, bf16_t* __restrict__ Z)
{
    __shared__ __align__(16) bf16_t Vt[2][16 * 72];   // [buf][d][key], stride 72

    const int tid  = threadIdx.x;
    const int wave = tid >> 6;        // 0..3
    const int lane = tid & 63;
    const int quad = lane >> 4;
    const int l16  = lane & 15;
    const int hd = blockIdx.x >> 3;
    const int qc = blockIdx.x & 7;
    const int a = hd >> 2, b = hd & 3;
    const int col0 = a * 16;
    const int qbase = qc * 128 + wave * 32;

    // Q as B-operand of S^T: B[n=q=l16][k=d=quad*8+j], quads 2,3 zero (d<16)
    bf16x8 qf[2] = {};
    if (quad < 2) {
        #pragma unroll
        for (int qs = 0; qs < 2; ++qs)
            qf[qs] = *(const bf16x8*)(Q +
                (size_t)(b * 1024 + qbase + qs * 16 + l16) * 1024 + col0 + quad * 8);
    }

    // K as A-operand of S^T: A[m=key=l16][k=d=quad*8+j], double-buffered regs
    const bf16_t* Kp = K + (size_t)(b * 1024 + l16) * 1024 + col0 + quad * 8;
    bf16x8 kf[2][4] = {};
    if (quad < 2) {
        #pragma unroll
        for (int kt = 0; kt < 4; ++kt)
            kf[0][kt] = *(const bf16x8*)(Kp + (size_t)(kt * 16) * 1024);
    }

    // V staging: thread (r = tid>>2, dq = (tid&3)*4) loads V[r][dq..dq+3],
    // writes transposed Vt[dq+ii][r].
    const int r  = tid >> 2;
    const int dq = (tid & 3) * 4;
    const bf16_t* Vp = V + (size_t)(b * 1024 + r) * 1024 + col0 + dq;

    uint2 vv = *(const uint2*)Vp;          // tile 0
    {
        bf16_t t4[4] __attribute__((aligned(8)));
        *(uint2*)t4 = vv;
        #pragma unroll
        for (int ii = 0; ii < 4; ++ii)
            Vt[0][(dq + ii) * 72 + r] = t4[ii];
    }
    vv = *(const uint2*)(Vp + (size_t)64 * 1024);   // prefetch tile 1
    __syncthreads();

    const s16x4 ones = { 0x3F80, 0x3F80, 0x3F80, 0x3F80 };  // bf16 1.0 x4

    f32x4 zacc[2] = {};
    f32x4 lacc[2] = {};

    #pragma unroll   // FULL unroll: cur/nxt compile-time -> kf stays in VGPRs
    for (int j = 0; j < 16; ++j) {
        const int cur = j & 1, nxt = cur ^ 1;

        // prefetch K frags for tile j+1
        if (j < 15 && quad < 2) {
            #pragma unroll
            for (int kt = 0; kt < 4; ++kt)
                kf[nxt][kt] = *(const bf16x8*)(Kp + (size_t)((j + 1) * 64 + kt * 16) * 1024);
        }
        // stage V tile j+1 into Vt[nxt]; prefetch V tile j+2
        if (j < 15) {
            bf16_t t4[4] __attribute__((aligned(8)));
            *(uint2*)t4 = vv;
            #pragma unroll
            for (int ii = 0; ii < 4; ++ii)
                Vt[nxt][(dq + ii) * 72 + r] = t4[ii];
            if (j < 14)
                vv = *(const uint2*)(Vp + (size_t)((j + 2) * 64) * 1024);
        }

        // compute on tile j
        #pragma unroll
        for (int kt = 0; kt < 4; ++kt) {
            // V^T A-frag: A[m=d=l16][k=key=quad*4+jj]
            const s16x4 vfrag = __builtin_bit_cast(s16x4,
                *(const uint2*)(&Vt[cur][l16 * 72 + kt * 16 + quad * 4]));
            #pragma unroll
            for (int qs = 0; qs < 2; ++qs) {
                f32x4 zc = {0.f, 0.f, 0.f, 0.f};
                f32x4 s = __builtin_amdgcn_mfma_f32_16x16x32_bf16(
                    kf[cur][kt], qf[qs], zc, 0, 0, 0);
                unsigned int u0 = __builtin_bit_cast(unsigned int,
                    __builtin_amdgcn_exp2f(s[0])) + 0x8000u;
                unsigned int u1 = __builtin_bit_cast(unsigned int,
                    __builtin_amdgcn_exp2f(s[1])) + 0x8000u;
                unsigned int u2 = __builtin_bit_cast(unsigned int,
                    __builtin_amdgcn_exp2f(s[2])) + 0x8000u;
                unsigned int u3 = __builtin_bit_cast(unsigned int,
                    __builtin_amdgcn_exp2f(s[3])) + 0x8000u;
                uint2 w;
                w.x = __builtin_amdgcn_perm(u1, u0, 0x07060302u);  // [bf16(p1)|bf16(p0)]
                w.y = __builtin_amdgcn_perm(u3, u2, 0x07060302u);
                const s16x4 pfrag = __builtin_bit_cast(s16x4, w);
                zacc[qs] = __builtin_amdgcn_mfma_f32_16x16x16bf16_1k(
                    vfrag, pfrag, zacc[qs], 0, 0, 0);
                lacc[qs] = __builtin_amdgcn_mfma_f32_16x16x16bf16_1k(
                    ones, pfrag, lacc[qs], 0, 0, 0);
            }
        }
        __syncthreads();
    }

    // epilogue: lane holds Z^T[d=quad*4+i][q=l16] and l[q] in lacc[qs][*]
    #pragma unroll
    for (int qs = 0; qs < 2; ++qs) {
        const float inv = 1.0f / lacc[qs][0];
        const int q = qbase + qs * 16 + l16;
        bf16_t o4[4] __attribute__((aligned(8)));
        #pragma unroll
        for (int i = 0; i < 4; ++i) o4[i] = (bf16_t)(zacc[qs][i] * inv);
        *(uint2*)(Z + ((size_t)hd * 1024 + q) * 16 + quad * 4) = *(const uint2*)o4;
    }
}

extern "C" void kernel_launch(void* const* d_in, const int* in_sizes, int n_in,
                              void* d_out, int out_size, void* d_ws, size_t ws_size,
                              hipStream_t stream) {
    const float* x  = (const float*)d_in[0];
    const float* Wq = (const float*)d_in[1];
    const float* bq = (const float*)d_in[2];
    const float* Wk = (const float*)d_in[3];
    const float* bk = (const float*)d_in[4];
    const float* Wv = (const float*)d_in[5];
    const float* bv = (const float*)d_in[6];
    const float* Wo = (const float*)d_in[7];
    const float* bo = (const float*)d_in[8];
    float* out = (float*)d_out;

    char* ws = (char*)d_ws;
    bf16_t* x_bf = (bf16_t*)(ws);
    bf16_t* Wt   = (bf16_t*)(ws + (8u << 20));   // q|k|v|o slabs, contiguous
    bf16_t* Qb   = (bf16_t*)(ws + (16u << 20));
    bf16_t* Kb   = (bf16_t*)(ws + (24u << 20));
    bf16_t* Vb   = (bf16_t*)(ws + (32u << 20));
    bf16_t* Zb   = (bf16_t*)(ws + (40u << 20));
    bf16_t* WtO  = Wt + (size_t)3 * 1024 * 1024;

    cast_f32_bf16<<<dim3(2048), dim3(256), 0, stream>>>(x, x_bf, 524288);
    transpose_cast<<<dim3(32, 32, 4), dim3(256), 0, stream>>>(Wq, Wk, Wv, Wo, Wt);

    // fused QKV: Bt = [3072][1024] (Wq|Wk|Wv)
    gemm_glds<true, 128><<<dim3(24, 32), dim3(256), 0, stream>>>(
        x_bf, Wt, bq, bk, bv, Qb, Kb, Vb, nullptr);

    attn_kernel<<<dim3(2048), dim3(256), 0, stream>>>(Qb, Kb, Vb, Zb);

    // O-projection: 64x128 tiles -> 512 blocks (2/CU)
    gemm_glds<false, 64><<<dim3(8, 64), dim3(256), 0, stream>>>(
        Zb, WtO, bo, nullptr, nullptr, nullptr, nullptr, nullptr, out);
}

// Round 4
// 197.005 us; speedup vs baseline: 1.4132x; 1.4132x over previous
//
#include <hip/hip_runtime.h>
#include <hip/hip_bf16.h>

// B=4, T=1024, E=1024, ATT=64, NH=16, AH=1024. M = B*T = 4096, K = N = 1024.
// Pipeline: cast x->bf16; transpose+cast W{q,k,v,o} -> [N][K] bf16;
//           fused QKV MFMA GEMM (128x128, global_load_lds, K-slab pre-scaled
//           by 0.125*log2e); register-path MFMA flash attention (S^T trick,
//           HW v_exp_f32); O-proj GEMM (64x128 -> 512 blocks).

typedef __bf16 bf16_t;
typedef bf16_t bf16x8 __attribute__((ext_vector_type(8)));
typedef short  s16x4 __attribute__((ext_vector_type(4)));
typedef float  f32x4 __attribute__((ext_vector_type(4)));

#define SCALE_LOG2E 0.18033688011112042f  /* 0.125 * log2(e) */

__device__ __forceinline__ void async16(const bf16_t* g, void* l) {
    __builtin_amdgcn_global_load_lds(
        (const __attribute__((address_space(1))) unsigned int*)g,
        (__attribute__((address_space(3))) unsigned int*)l,
        16, 0, 0);
}

// ---------- cast fp32 -> bf16, 8 elems/thread ----------
__global__ __launch_bounds__(256) void cast_f32_bf16(
    const float* __restrict__ in, bf16_t* __restrict__ out, int n8)
{
    int i = blockIdx.x * 256 + threadIdx.x;
    if (i >= n8) return;
    const float4* p = (const float4*)in + (size_t)i * 2;
    float4 a = p[0], b = p[1];
    bf16x8 o;
    o[0] = (bf16_t)a.x; o[1] = (bf16_t)a.y; o[2] = (bf16_t)a.z; o[3] = (bf16_t)a.w;
    o[4] = (bf16_t)b.x; o[5] = (bf16_t)b.y; o[6] = (bf16_t)b.z; o[7] = (bf16_t)b.w;
    *((bf16x8*)out + i) = o;
}

// ---------- transpose + cast: W [1024][1024] fp32 [K][N] -> [N][K] bf16 ----------
__global__ __launch_bounds__(256) void transpose_cast(
    const float* __restrict__ W0, const float* __restrict__ W1,
    const float* __restrict__ W2, const float* __restrict__ W3,
    bf16_t* __restrict__ out)
{
    __shared__ float st[32][33];
    const float* W = (blockIdx.z == 0) ? W0 : (blockIdx.z == 1) ? W1
                   : (blockIdx.z == 2) ? W2 : W3;
    bf16_t* o = out + (size_t)blockIdx.z * 1024 * 1024;
    const int n0 = blockIdx.x * 32, k0 = blockIdx.y * 32;
    const int t = threadIdx.x;
    const int r = t >> 3, c4 = (t & 7) * 4;
    float4 v = *(const float4*)(W + (size_t)(k0 + r) * 1024 + n0 + c4);
    st[r][c4 + 0] = v.x; st[r][c4 + 1] = v.y; st[r][c4 + 2] = v.z; st[r][c4 + 3] = v.w;
    __syncthreads();
    bf16_t tmp[4] __attribute__((aligned(8)));
    #pragma unroll
    for (int i = 0; i < 4; ++i) tmp[i] = (bf16_t)st[c4 + i][r];
    *(uint2*)(o + (size_t)(n0 + r) * 1024 + k0 + c4) = *(const uint2*)tmp;
}

// ---------- MFMA GEMM: C = A[M,1024] @ Bt[N,1024]^T + bias ----------
template<bool FUSED, int MT>
__global__ __launch_bounds__(256, 3) void gemm_glds(
    const bf16_t* __restrict__ A, const bf16_t* __restrict__ Bt,
    const float* __restrict__ b0, const float* __restrict__ b1,
    const float* __restrict__ b2,
    bf16_t* __restrict__ Qo, bf16_t* __restrict__ Ko, bf16_t* __restrict__ Vo,
    float* __restrict__ Fo)
{
    const int K = 1024;
    __shared__ __align__(16) bf16_t As[MT * 32];
    __shared__ __align__(16) bf16_t Bs[128 * 32];

    constexpr int NTPW = (MT == 128) ? 4 : 2;
    constexpr int JA   = MT / 64;

    const int tid  = threadIdx.x;
    const int wave = tid >> 6;
    const int lane = tid & 63;
    const int quad = lane >> 4;
    const int l16  = lane & 15;
    const int m0 = blockIdx.y * MT;
    const int n0 = blockIdx.x * 128;
    const int wm = (MT == 128) ? (wave >> 1) * 64 : 0;
    const int wn = (MT == 128) ? (wave & 1) * 64 : wave * 32;

    int goffA[JA], goffB[2];
    #pragma unroll
    for (int j = 0; j < JA; ++j) {
        const int row = j * 64 + (tid >> 2);
        const int cl  = (tid & 3) ^ ((row >> 1) & 3);
        goffA[j] = (m0 + row) * K + cl * 8;
    }
    #pragma unroll
    for (int j = 0; j < 2; ++j) {
        const int row = j * 64 + (tid >> 2);
        const int cl  = (tid & 3) ^ ((row >> 1) & 3);
        goffB[j] = (n0 + row) * K + cl * 8;
    }
    const int ldsoff = wave * 1024;

    f32x4 acc[4][NTPW] = {};
    const int sw = (l16 >> 1) & 3;

    for (int k0 = 0; k0 < K; k0 += 32) {
        #pragma unroll
        for (int j = 0; j < JA; ++j)
            async16(A + goffA[j] + k0, (char*)As + j * 4096 + ldsoff);
        #pragma unroll
        for (int j = 0; j < 2; ++j)
            async16(Bt + goffB[j] + k0, (char*)Bs + j * 4096 + ldsoff);
        __syncthreads();

        bf16x8 af[4], bfr[NTPW];
        #pragma unroll
        for (int mt = 0; mt < 4; ++mt)
            af[mt] = *(const bf16x8*)(&As[(wm + mt * 16 + l16) * 32 + (quad ^ sw) * 8]);
        #pragma unroll
        for (int nt = 0; nt < NTPW; ++nt)
            bfr[nt] = *(const bf16x8*)(&Bs[(wn + nt * 16 + l16) * 32 + (quad ^ sw) * 8]);
        #pragma unroll
        for (int mt = 0; mt < 4; ++mt)
            #pragma unroll
            for (int nt = 0; nt < NTPW; ++nt)
                acc[mt][nt] = __builtin_amdgcn_mfma_f32_16x16x32_bf16(
                    af[mt], bfr[nt], acc[mt][nt], 0, 0, 0);
        __syncthreads();
    }

    if (FUSED) {
        const int sel = n0 >> 10;
        const float* bias = (sel == 0) ? b0 : (sel == 1) ? b1 : b2;
        bf16_t* Cout      = (sel == 0) ? Qo : (sel == 1) ? Ko : Vo;
        const float scl   = (sel == 1) ? SCALE_LOG2E : 1.0f;
        const int nb = n0 & 1023;
        #pragma unroll
        for (int nt = 0; nt < NTPW; ++nt) {
            const int n = nb + wn + nt * 16 + l16;
            const float bb = bias[n];
            #pragma unroll
            for (int mt = 0; mt < 4; ++mt)
                #pragma unroll
                for (int i = 0; i < 4; ++i) {
                    const int m = m0 + wm + mt * 16 + quad * 4 + i;
                    Cout[(size_t)m * 1024 + n] = (bf16_t)((acc[mt][nt][i] + bb) * scl);
                }
        }
    } else {
        #pragma unroll
        for (int nt = 0; nt < NTPW; ++nt) {
            const int n = n0 + wn + nt * 16 + l16;
            const float bb = b0[n];
            #pragma unroll
            for (int mt = 0; mt < 4; ++mt)
                #pragma unroll
                for (int i = 0; i < 4; ++i) {
                    const int m = m0 + wm + mt * 16 + quad * 4 + i;
                    Fo[(size_t)m * 1024 + n] = acc[mt][nt][i] + bb;
                }
        }
    }
}

// ---------- MFMA flash attention, register-path P, HW exp ----------
// Grid 2048: (head hd = bx>>3, q-chunk qc = bx&7). 256 thr = 4 waves, wave
// owns 32 q rows (2 q-subs of 16). launch_bounds(256,6) -> 6 blocks/CU =
// 24 waves/CU resident, VGPR budget 512/6=85 regs/lane.
// ROUND-3 LESSON: (256,8) capped the unified VGPR+AGPR budget at 64 while
// live state is ~80 -> allocator split 32V+32A and spilled the K
// double-buffer to scratch (WRITE_SIZE 9MB->305MB, attn 57->142us). The
// budget knob, not occupancy, was binding.
// Compute core is VERBATIM round-0 (proven on HW at 191.6us): K pre-scaled
// by 0.125*log2e; S^T = K.Q^T (swap operands) via mfma_f32_16x16x32_bf16
// with quads 2-3 zeroed (d=16); C-layout of S^T gives lane q=l16,
// keys=quad*4+i == B-operand layout of v_mfma_f32_16x16x16bf16_1k.
// p = exp2(s) packed in-register (+0x8000 round, 2 v_perm) feeds
// Z^T = V^T.P^T and l = 1.P^T directly. exp via __builtin_amdgcn_exp2f =
// bare v_exp_f32. j-loop fully unrolled so double-buffer regs stay in
// VGPRs. NOTE rounds 1-2 (NaN, reverted): QK via 16x16x16bf16_1k +
// inline-asm v_cvt_pk_bf16_f32. Do not reintroduce without isolating.
__global__ __launch_bounds__(256, 6) void attn_kernel(
    const bf16_t* __restrict__ Q, const bf16_t* __restrict__ K,
    const bf16_t* __restrict__ V, bf16_t* __restrict__ Z)
{
    __shared__ __align__(16) bf16_t Vt[2][16 * 72];   // [buf][d][key], stride 72

    const int tid  = threadIdx.x;
    const int wave = tid >> 6;        // 0..3
    const int lane = tid & 63;
    const int quad = lane >> 4;
    const int l16  = lane & 15;
    const int hd = blockIdx.x >> 3;
    const int qc = blockIdx.x & 7;
    const int a = hd >> 2, b = hd & 3;
    const int col0 = a * 16;
    const int qbase = qc * 128 + wave * 32;

    // Q as B-operand of S^T: B[n=q=l16][k=d=quad*8+j], quads 2,3 zero (d<16)
    bf16x8 qf[2] = {};
    if (quad < 2) {
        #pragma unroll
        for (int qs = 0; qs < 2; ++qs)
            qf[qs] = *(const bf16x8*)(Q +
                (size_t)(b * 1024 + qbase + qs * 16 + l16) * 1024 + col0 + quad * 8);
    }

    // K as A-operand of S^T: A[m=key=l16][k=d=quad*8+j], double-buffered regs
    const bf16_t* Kp = K + (size_t)(b * 1024 + l16) * 1024 + col0 + quad * 8;
    bf16x8 kf[2][4] = {};
    if (quad < 2) {
        #pragma unroll
        for (int kt = 0; kt < 4; ++kt)
            kf[0][kt] = *(const bf16x8*)(Kp + (size_t)(kt * 16) * 1024);
    }

    // V staging: thread (r = tid>>2, dq = (tid&3)*4) loads V[r][dq..dq+3],
    // writes transposed Vt[dq+ii][r].
    const int r  = tid >> 2;
    const int dq = (tid & 3) * 4;
    const bf16_t* Vp = V + (size_t)(b * 1024 + r) * 1024 + col0 + dq;

    uint2 vv = *(const uint2*)Vp;          // tile 0
    {
        bf16_t t4[4] __attribute__((aligned(8)));
        *(uint2*)t4 = vv;
        #pragma unroll
        for (int ii = 0; ii < 4; ++ii)
            Vt[0][(dq + ii) * 72 + r] = t4[ii];
    }
    vv = *(const uint2*)(Vp + (size_t)64 * 1024);   // prefetch tile 1
    __syncthreads();

    const s16x4 ones = { 0x3F80, 0x3F80, 0x3F80, 0x3F80 };  // bf16 1.0 x4

    f32x4 zacc[2] = {};
    f32x4 lacc[2] = {};

    #pragma unroll   // FULL unroll: cur/nxt compile-time -> kf stays in VGPRs
    for (int j = 0; j < 16; ++j) {
        const int cur = j & 1, nxt = cur ^ 1;

        // prefetch K frags for tile j+1
        if (j < 15 && quad < 2) {
            #pragma unroll
            for (int kt = 0; kt < 4; ++kt)
                kf[nxt][kt] = *(const bf16x8*)(Kp + (size_t)((j + 1) * 64 + kt * 16) * 1024);
        }
        // stage V tile j+1 into Vt[nxt]; prefetch V tile j+2
        if (j < 15) {
            bf16_t t4[4] __attribute__((aligned(8)));
            *(uint2*)t4 = vv;
            #pragma unroll
            for (int ii = 0; ii < 4; ++ii)
                Vt[nxt][(dq + ii) * 72 + r] = t4[ii];
            if (j < 14)
                vv = *(const uint2*)(Vp + (size_t)((j + 2) * 64) * 1024);
        }

        // compute on tile j
        #pragma unroll
        for (int kt = 0; kt < 4; ++kt) {
            // V^T A-frag: A[m=d=l16][k=key=quad*4+jj]
            const s16x4 vfrag = __builtin_bit_cast(s16x4,
                *(const uint2*)(&Vt[cur][l16 * 72 + kt * 16 + quad * 4]));
            #pragma unroll
            for (int qs = 0; qs < 2; ++qs) {
                f32x4 zc = {0.f, 0.f, 0.f, 0.f};
                f32x4 s = __builtin_amdgcn_mfma_f32_16x16x32_bf16(
                    kf[cur][kt], qf[qs], zc, 0, 0, 0);
                unsigned int u0 = __builtin_bit_cast(unsigned int,
                    __builtin_amdgcn_exp2f(s[0])) + 0x8000u;
                unsigned int u1 = __builtin_bit_cast(unsigned int,
                    __builtin_amdgcn_exp2f(s[1])) + 0x8000u;
                unsigned int u2 = __builtin_bit_cast(unsigned int,
                    __builtin_amdgcn_exp2f(s[2])) + 0x8000u;
                unsigned int u3 = __builtin_bit_cast(unsigned int,
                    __builtin_amdgcn_exp2f(s[3])) + 0x8000u;
                uint2 w;
                w.x = __builtin_amdgcn_perm(u1, u0, 0x07060302u);  // [bf16(p1)|bf16(p0)]
                w.y = __builtin_amdgcn_perm(u3, u2, 0x07060302u);
                const s16x4 pfrag = __builtin_bit_cast(s16x4, w);
                zacc[qs] = __builtin_amdgcn_mfma_f32_16x16x16bf16_1k(
                    vfrag, pfrag, zacc[qs], 0, 0, 0);
                lacc[qs] = __builtin_amdgcn_mfma_f32_16x16x16bf16_1k(
                    ones, pfrag, lacc[qs], 0, 0, 0);
            }
        }
        __syncthreads();
    }

    // epilogue: lane holds Z^T[d=quad*4+i][q=l16] and l[q] in lacc[qs][*]
    #pragma unroll
    for (int qs = 0; qs < 2; ++qs) {
        const float inv = 1.0f / lacc[qs][0];
        const int q = qbase + qs * 16 + l16;
        bf16_t o4[4] __attribute__((aligned(8)));
        #pragma unroll
        for (int i = 0; i < 4; ++i) o4[i] = (bf16_t)(zacc[qs][i] * inv);
        *(uint2*)(Z + ((size_t)hd * 1024 + q) * 16 + quad * 4) = *(const uint2*)o4;
    }
}

extern "C" void kernel_launch(void* const* d_in, const int* in_sizes, int n_in,
                              void* d_out, int out_size, void* d_ws, size_t ws_size,
                              hipStream_t stream) {
    const float* x  = (const float*)d_in[0];
    const float* Wq = (const float*)d_in[1];
    const float* bq = (const float*)d_in[2];
    const float* Wk = (const float*)d_in[3];
    const float* bk = (const float*)d_in[4];
    const float* Wv = (const float*)d_in[5];
    const float* bv = (const float*)d_in[6];
    const float* Wo = (const float*)d_in[7];
    const float* bo = (const float*)d_in[8];
    float* out = (float*)d_out;

    char* ws = (char*)d_ws;
    bf16_t* x_bf = (bf16_t*)(ws);
    bf16_t* Wt   = (bf16_t*)(ws + (8u << 20));   // q|k|v|o slabs, contiguous
    bf16_t* Qb   = (bf16_t*)(ws + (16u << 20));
    bf16_t* Kb   = (bf16_t*)(ws + (24u << 20));
    bf16_t* Vb   = (bf16_t*)(ws + (32u << 20));
    bf16_t* Zb   = (bf16_t*)(ws + (40u << 20));
    bf16_t* WtO  = Wt + (size_t)3 * 1024 * 1024;

    cast_f32_bf16<<<dim3(2048), dim3(256), 0, stream>>>(x, x_bf, 524288);
    transpose_cast<<<dim3(32, 32, 4), dim3(256), 0, stream>>>(Wq, Wk, Wv, Wo, Wt);

    // fused QKV: Bt = [3072][1024] (Wq|Wk|Wv)
    gemm_glds<true, 128><<<dim3(24, 32), dim3(256), 0, stream>>>(
        x_bf, Wt, bq, bk, bv, Qb, Kb, Vb, nullptr);

    attn_kernel<<<dim3(2048), dim3(256), 0, stream>>>(Qb, Kb, Vb, Zb);

    // O-projection: 64x128 tiles -> 512 blocks (2/CU)
    gemm_glds<false, 64><<<dim3(8, 64), dim3(256), 0, stream>>>(
        Zb, WtO, bo, nullptr, nullptr, nullptr, nullptr, nullptr, out);
}

// Round 5
// 193.762 us; speedup vs baseline: 1.4369x; 1.0167x over previous
//
#include <hip/hip_runtime.h>
#include <hip/hip_bf16.h>

// B=4, T=1024, E=1024, ATT=64, NH=16, AH=1024. M = B*T = 4096, K = N = 1024.
// Pipeline: cast x->bf16; transpose+cast W{q,k,v,o} -> [N][K] bf16;
//           fused QKV MFMA GEMM (128x128, global_load_lds, K-slab pre-scaled
//           by 0.125*log2e); register-path MFMA flash attention (S^T trick,
//           HW v_exp_f32); O-proj GEMM (64x128 -> 512 blocks).

typedef __bf16 bf16_t;
typedef bf16_t bf16x8 __attribute__((ext_vector_type(8)));
typedef short  s16x4 __attribute__((ext_vector_type(4)));
typedef float  f32x4 __attribute__((ext_vector_type(4)));

#define SCALE_LOG2E 0.18033688011112042f  /* 0.125 * log2(e) */

__device__ __forceinline__ void async16(const bf16_t* g, void* l) {
    __builtin_amdgcn_global_load_lds(
        (const __attribute__((address_space(1))) unsigned int*)g,
        (__attribute__((address_space(3))) unsigned int*)l,
        16, 0, 0);
}

// Barrier that does NOT drain vmcnt: waits only for our own LDS ops
// (write-visibility of Vt[nxt] + WAR safety of Vt[cur] reads), then raw
// s_barrier. __syncthreads() would emit s_waitcnt vmcnt(0) first, draining
// the in-flight K/V global prefetch every tile (the m97-structure ~20%
// stall). Register-destined global loads are safe across the barrier; the
// compiler still inserts vmcnt before their first use.
__device__ __forceinline__ void lds_barrier() {
    asm volatile("s_waitcnt lgkmcnt(0)" ::: "memory");
    __builtin_amdgcn_s_barrier();
}

// ---------- cast fp32 -> bf16, 8 elems/thread ----------
__global__ __launch_bounds__(256) void cast_f32_bf16(
    const float* __restrict__ in, bf16_t* __restrict__ out, int n8)
{
    int i = blockIdx.x * 256 + threadIdx.x;
    if (i >= n8) return;
    const float4* p = (const float4*)in + (size_t)i * 2;
    float4 a = p[0], b = p[1];
    bf16x8 o;
    o[0] = (bf16_t)a.x; o[1] = (bf16_t)a.y; o[2] = (bf16_t)a.z; o[3] = (bf16_t)a.w;
    o[4] = (bf16_t)b.x; o[5] = (bf16_t)b.y; o[6] = (bf16_t)b.z; o[7] = (bf16_t)b.w;
    *((bf16x8*)out + i) = o;
}

// ---------- transpose + cast: W [1024][1024] fp32 [K][N] -> [N][K] bf16 ----------
__global__ __launch_bounds__(256) void transpose_cast(
    const float* __restrict__ W0, const float* __restrict__ W1,
    const float* __restrict__ W2, const float* __restrict__ W3,
    bf16_t* __restrict__ out)
{
    __shared__ float st[32][33];
    const float* W = (blockIdx.z == 0) ? W0 : (blockIdx.z == 1) ? W1
                   : (blockIdx.z == 2) ? W2 : W3;
    bf16_t* o = out + (size_t)blockIdx.z * 1024 * 1024;
    const int n0 = blockIdx.x * 32, k0 = blockIdx.y * 32;
    const int t = threadIdx.x;
    const int r = t >> 3, c4 = (t & 7) * 4;
    float4 v = *(const float4*)(W + (size_t)(k0 + r) * 1024 + n0 + c4);
    st[r][c4 + 0] = v.x; st[r][c4 + 1] = v.y; st[r][c4 + 2] = v.z; st[r][c4 + 3] = v.w;
    __syncthreads();
    bf16_t tmp[4] __attribute__((aligned(8)));
    #pragma unroll
    for (int i = 0; i < 4; ++i) tmp[i] = (bf16_t)st[c4 + i][r];
    *(uint2*)(o + (size_t)(n0 + r) * 1024 + k0 + c4) = *(const uint2*)tmp;
}

// ---------- MFMA GEMM: C = A[M,1024] @ Bt[N,1024]^T + bias ----------
template<bool FUSED, int MT>
__global__ __launch_bounds__(256, 3) void gemm_glds(
    const bf16_t* __restrict__ A, const bf16_t* __restrict__ Bt,
    const float* __restrict__ b0, const float* __restrict__ b1,
    const float* __restrict__ b2,
    bf16_t* __restrict__ Qo, bf16_t* __restrict__ Ko, bf16_t* __restrict__ Vo,
    float* __restrict__ Fo)
{
    const int K = 1024;
    __shared__ __align__(16) bf16_t As[MT * 32];
    __shared__ __align__(16) bf16_t Bs[128 * 32];

    constexpr int NTPW = (MT == 128) ? 4 : 2;
    constexpr int JA   = MT / 64;

    const int tid  = threadIdx.x;
    const int wave = tid >> 6;
    const int lane = tid & 63;
    const int quad = lane >> 4;
    const int l16  = lane & 15;
    const int m0 = blockIdx.y * MT;
    const int n0 = blockIdx.x * 128;
    const int wm = (MT == 128) ? (wave >> 1) * 64 : 0;
    const int wn = (MT == 128) ? (wave & 1) * 64 : wave * 32;

    int goffA[JA], goffB[2];
    #pragma unroll
    for (int j = 0; j < JA; ++j) {
        const int row = j * 64 + (tid >> 2);
        const int cl  = (tid & 3) ^ ((row >> 1) & 3);
        goffA[j] = (m0 + row) * K + cl * 8;
    }
    #pragma unroll
    for (int j = 0; j < 2; ++j) {
        const int row = j * 64 + (tid >> 2);
        const int cl  = (tid & 3) ^ ((row >> 1) & 3);
        goffB[j] = (n0 + row) * K + cl * 8;
    }
    const int ldsoff = wave * 1024;

    f32x4 acc[4][NTPW] = {};
    const int sw = (l16 >> 1) & 3;

    for (int k0 = 0; k0 < K; k0 += 32) {
        #pragma unroll
        for (int j = 0; j < JA; ++j)
            async16(A + goffA[j] + k0, (char*)As + j * 4096 + ldsoff);
        #pragma unroll
        for (int j = 0; j < 2; ++j)
            async16(Bt + goffB[j] + k0, (char*)Bs + j * 4096 + ldsoff);
        __syncthreads();

        bf16x8 af[4], bfr[NTPW];
        #pragma unroll
        for (int mt = 0; mt < 4; ++mt)
            af[mt] = *(const bf16x8*)(&As[(wm + mt * 16 + l16) * 32 + (quad ^ sw) * 8]);
        #pragma unroll
        for (int nt = 0; nt < NTPW; ++nt)
            bfr[nt] = *(const bf16x8*)(&Bs[(wn + nt * 16 + l16) * 32 + (quad ^ sw) * 8]);
        #pragma unroll
        for (int mt = 0; mt < 4; ++mt)
            #pragma unroll
            for (int nt = 0; nt < NTPW; ++nt)
                acc[mt][nt] = __builtin_amdgcn_mfma_f32_16x16x32_bf16(
                    af[mt], bfr[nt], acc[mt][nt], 0, 0, 0);
        __syncthreads();
    }

    if (FUSED) {
        const int sel = n0 >> 10;
        const float* bias = (sel == 0) ? b0 : (sel == 1) ? b1 : b2;
        bf16_t* Cout      = (sel == 0) ? Qo : (sel == 1) ? Ko : Vo;
        const float scl   = (sel == 1) ? SCALE_LOG2E : 1.0f;
        const int nb = n0 & 1023;
        #pragma unroll
        for (int nt = 0; nt < NTPW; ++nt) {
            const int n = nb + wn + nt * 16 + l16;
            const float bb = bias[n];
            #pragma unroll
            for (int mt = 0; mt < 4; ++mt)
                #pragma unroll
                for (int i = 0; i < 4; ++i) {
                    const int m = m0 + wm + mt * 16 + quad * 4 + i;
                    Cout[(size_t)m * 1024 + n] = (bf16_t)((acc[mt][nt][i] + bb) * scl);
                }
        }
    } else {
        #pragma unroll
        for (int nt = 0; nt < NTPW; ++nt) {
            const int n = n0 + wn + nt * 16 + l16;
            const float bb = b0[n];
            #pragma unroll
            for (int mt = 0; mt < 4; ++mt)
                #pragma unroll
                for (int i = 0; i < 4; ++i) {
                    const int m = m0 + wm + mt * 16 + quad * 4 + i;
                    Fo[(size_t)m * 1024 + n] = acc[mt][nt][i] + bb;
                }
        }
    }
}

// ---------- MFMA flash attention, register-path P, HW exp ----------
// ROUND-0 STRUCTURE RESTORED (proven 57.3us): grid 1024 (head hd = bx>>2,
// q-chunk qc = bx&3), 256 thr = 4 waves, wave owns 64 q rows (4 q-subs).
// ROUND-4 LESSON: splitting q into more chunks (grid 2048) raised occupancy
// 29->44% but halved arithmetic intensity (FETCH 37.6->70.8 MB) -> net
// SLOWER (63.6us). Work partition stays as round 0.
// THIS ROUND'S ONE CHANGE: per-tile __syncthreads -> lds_barrier()
// (s_waitcnt lgkmcnt(0) + raw s_barrier). __syncthreads emits
// s_waitcnt vmcnt(0) before s_barrier, draining the in-flight K/V global
// prefetch at every one of the 16 tiles (the m97-structure barrier-drain
// stall). lgkmcnt(0) alone is sufficient for correctness: it makes our
// Vt[nxt] writes visible and completes our Vt[cur] reads (WAR) before the
// barrier; K/V global loads target registers only, and the compiler still
// inserts vmcnt before their first use in the next tile.
// Core: K pre-scaled by 0.125*log2e; S^T = K.Q^T via mfma_f32_16x16x32_bf16
// (quads 2-3 zero, d=16); C-layout of S^T = B-operand layout of
// v_mfma_f32_16x16x16bf16_1k; p = exp2(s) packed (+0x8000, 2 v_perm);
// Z^T = V^T.P^T, l = 1.P^T. exp = __builtin_amdgcn_exp2f (bare v_exp_f32).
// j-loop fully unrolled. NOTE rounds 1-2 (NaN): 16x16x16bf16_1k QK +
// inline-asm v_cvt_pk_bf16_f32 — not isolated, do not reintroduce blind.
__global__ __launch_bounds__(256, 4) void attn_kernel(
    const bf16_t* __restrict__ Q, const bf16_t* __restrict__ K,
    const bf16_t* __restrict__ V, bf16_t* __restrict__ Z)
{
    __shared__ __align__(16) bf16_t Vt[2][16 * 72];   // [buf][d][key], stride 72

    const int tid  = threadIdx.x;
    const int wave = tid >> 6;
    const int lane = tid & 63;
    const int quad = lane >> 4;
    const int l16  = lane & 15;
    const int hd = blockIdx.x >> 2;
    const int qc = blockIdx.x & 3;
    const int a = hd >> 2, b = hd & 3;
    const int col0 = a * 16;
    const int qbase = qc * 256 + wave * 64;

    // Q as B-operand of S^T: B[n=q=l16][k=d=quad*8+j], quads 2,3 zero (d<16)
    bf16x8 qf[4] = {};
    if (quad < 2) {
        #pragma unroll
        for (int qs = 0; qs < 4; ++qs)
            qf[qs] = *(const bf16x8*)(Q +
                (size_t)(b * 1024 + qbase + qs * 16 + l16) * 1024 + col0 + quad * 8);
    }

    // K as A-operand of S^T: A[m=key=l16][k=d=quad*8+j], double-buffered regs
    const bf16_t* Kp = K + (size_t)(b * 1024 + l16) * 1024 + col0 + quad * 8;
    bf16x8 kf[2][4] = {};
    if (quad < 2) {
        #pragma unroll
        for (int kt = 0; kt < 4; ++kt)
            kf[0][kt] = *(const bf16x8*)(Kp + (size_t)(kt * 16) * 1024);
    }

    // V staging: thread (r = tid>>2, dq = (tid&3)*4) loads V[r][dq..dq+3],
    // writes transposed Vt[dq+ii][r].
    const int r  = tid >> 2;
    const int dq = (tid & 3) * 4;
    const bf16_t* Vp = V + (size_t)(b * 1024 + r) * 1024 + col0 + dq;

    uint2 vv = *(const uint2*)Vp;          // tile 0
    {
        bf16_t t4[4] __attribute__((aligned(8)));
        *(uint2*)t4 = vv;
        #pragma unroll
        for (int ii = 0; ii < 4; ++ii)
            Vt[0][(dq + ii) * 72 + r] = t4[ii];
    }
    vv = *(const uint2*)(Vp + (size_t)64 * 1024);   // prefetch tile 1
    lds_barrier();

    const s16x4 ones = { 0x3F80, 0x3F80, 0x3F80, 0x3F80 };  // bf16 1.0 x4

    f32x4 zacc[4] = {};
    f32x4 lacc[4] = {};

    #pragma unroll   // FULL unroll: cur/nxt compile-time -> kf stays in VGPRs
    for (int j = 0; j < 16; ++j) {
        const int cur = j & 1, nxt = cur ^ 1;

        // prefetch K frags for tile j+1
        if (j < 15 && quad < 2) {
            #pragma unroll
            for (int kt = 0; kt < 4; ++kt)
                kf[nxt][kt] = *(const bf16x8*)(Kp + (size_t)((j + 1) * 64 + kt * 16) * 1024);
        }
        // stage V tile j+1 into Vt[nxt]; prefetch V tile j+2
        if (j < 15) {
            bf16_t t4[4] __attribute__((aligned(8)));
            *(uint2*)t4 = vv;
            #pragma unroll
            for (int ii = 0; ii < 4; ++ii)
                Vt[nxt][(dq + ii) * 72 + r] = t4[ii];
            if (j < 14)
                vv = *(const uint2*)(Vp + (size_t)((j + 2) * 64) * 1024);
        }

        // compute on tile j
        #pragma unroll
        for (int kt = 0; kt < 4; ++kt) {
            // V^T A-frag: A[m=d=l16][k=key=quad*4+jj]
            const s16x4 vfrag = __builtin_bit_cast(s16x4,
                *(const uint2*)(&Vt[cur][l16 * 72 + kt * 16 + quad * 4]));
            #pragma unroll
            for (int qs = 0; qs < 4; ++qs) {
                f32x4 zc = {0.f, 0.f, 0.f, 0.f};
                f32x4 s = __builtin_amdgcn_mfma_f32_16x16x32_bf16(
                    kf[cur][kt], qf[qs], zc, 0, 0, 0);
                unsigned int u0 = __builtin_bit_cast(unsigned int,
                    __builtin_amdgcn_exp2f(s[0])) + 0x8000u;
                unsigned int u1 = __builtin_bit_cast(unsigned int,
                    __builtin_amdgcn_exp2f(s[1])) + 0x8000u;
                unsigned int u2 = __builtin_bit_cast(unsigned int,
                    __builtin_amdgcn_exp2f(s[2])) + 0x8000u;
                unsigned int u3 = __builtin_bit_cast(unsigned int,
                    __builtin_amdgcn_exp2f(s[3])) + 0x8000u;
                uint2 w;
                w.x = __builtin_amdgcn_perm(u1, u0, 0x07060302u);  // [bf16(p1)|bf16(p0)]
                w.y = __builtin_amdgcn_perm(u3, u2, 0x07060302u);
                const s16x4 pfrag = __builtin_bit_cast(s16x4, w);
                zacc[qs] = __builtin_amdgcn_mfma_f32_16x16x16bf16_1k(
                    vfrag, pfrag, zacc[qs], 0, 0, 0);
                lacc[qs] = __builtin_amdgcn_mfma_f32_16x16x16bf16_1k(
                    ones, pfrag, lacc[qs], 0, 0, 0);
            }
        }
        lds_barrier();
    }

    // epilogue: lane holds Z^T[d=quad*4+i][q=l16] and l[q] in lacc[qs][*]
    #pragma unroll
    for (int qs = 0; qs < 4; ++qs) {
        const float inv = 1.0f / lacc[qs][0];
        const int q = qbase + qs * 16 + l16;
        bf16_t o4[4] __attribute__((aligned(8)));
        #pragma unroll
        for (int i = 0; i < 4; ++i) o4[i] = (bf16_t)(zacc[qs][i] * inv);
        *(uint2*)(Z + ((size_t)hd * 1024 + q) * 16 + quad * 4) = *(const uint2*)o4;
    }
}

extern "C" void kernel_launch(void* const* d_in, const int* in_sizes, int n_in,
                              void* d_out, int out_size, void* d_ws, size_t ws_size,
                              hipStream_t stream) {
    const float* x  = (const float*)d_in[0];
    const float* Wq = (const float*)d_in[1];
    const float* bq = (const float*)d_in[2];
    const float* Wk = (const float*)d_in[3];
    const float* bk = (const float*)d_in[4];
    const float* Wv = (const float*)d_in[5];
    const float* bv = (const float*)d_in[6];
    const float* Wo = (const float*)d_in[7];
    const float* bo = (const float*)d_in[8];
    float* out = (float*)d_out;

    char* ws = (char*)d_ws;
    bf16_t* x_bf = (bf16_t*)(ws);
    bf16_t* Wt   = (bf16_t*)(ws + (8u << 20));   // q|k|v|o slabs, contiguous
    bf16_t* Qb   = (bf16_t*)(ws + (16u << 20));
    bf16_t* Kb   = (bf16_t*)(ws + (24u << 20));
    bf16_t* Vb   = (bf16_t*)(ws + (32u << 20));
    bf16_t* Zb   = (bf16_t*)(ws + (40u << 20));
    bf16_t* WtO  = Wt + (size_t)3 * 1024 * 1024;

    cast_f32_bf16<<<dim3(2048), dim3(256), 0, stream>>>(x, x_bf, 524288);
    transpose_cast<<<dim3(32, 32, 4), dim3(256), 0, stream>>>(Wq, Wk, Wv, Wo, Wt);

    // fused QKV: Bt = [3072][1024] (Wq|Wk|Wv)
    gemm_glds<true, 128><<<dim3(24, 32), dim3(256), 0, stream>>>(
        x_bf, Wt, bq, bk, bv, Qb, Kb, Vb, nullptr);

    attn_kernel<<<dim3(1024), dim3(256), 0, stream>>>(Qb, Kb, Vb, Zb);

    // O-projection: 64x128 tiles -> 512 blocks (2/CU)
    gemm_glds<false, 64><<<dim3(8, 64), dim3(256), 0, stream>>>(
        Zb, WtO, bo, nullptr, nullptr, nullptr, nullptr, nullptr, out);
}

// Round 7
// 192.197 us; speedup vs baseline: 1.4486x; 1.0081x over previous
//
#include <hip/hip_runtime.h>
#include <hip/hip_bf16.h>

// B=4, T=1024, E=1024, ATT=64, NH=16, AH=1024. M = B*T = 4096, K = N = 1024.
// Pipeline: cast x->bf16; transpose+cast W{q,k,v,o} -> [N][K] bf16;
//           fused QKV MFMA GEMM (128x128, global_load_lds, K-slab pre-scaled
//           by 0.125*log2e); register-path MFMA flash attention (S^T trick,
//           HW v_exp_f32); O-proj GEMM (64x128 -> 512 blocks).

typedef __bf16 bf16_t;
typedef bf16_t bf16x8 __attribute__((ext_vector_type(8)));
typedef short  s16x4 __attribute__((ext_vector_type(4)));
typedef float  f32x4 __attribute__((ext_vector_type(4)));

#define SCALE_LOG2E 0.18033688011112042f  /* 0.125 * log2(e) */

__device__ __forceinline__ void async16(const bf16_t* g, void* l) {
    __builtin_amdgcn_global_load_lds(
        (const __attribute__((address_space(1))) unsigned int*)g,
        (__attribute__((address_space(3))) unsigned int*)l,
        16, 0, 0);
}

// ---------- cast fp32 -> bf16, 8 elems/thread ----------
__global__ __launch_bounds__(256) void cast_f32_bf16(
    const float* __restrict__ in, bf16_t* __restrict__ out, int n8)
{
    int i = blockIdx.x * 256 + threadIdx.x;
    if (i >= n8) return;
    const float4* p = (const float4*)in + (size_t)i * 2;
    float4 a = p[0], b = p[1];
    bf16x8 o;
    o[0] = (bf16_t)a.x; o[1] = (bf16_t)a.y; o[2] = (bf16_t)a.z; o[3] = (bf16_t)a.w;
    o[4] = (bf16_t)b.x; o[5] = (bf16_t)b.y; o[6] = (bf16_t)b.z; o[7] = (bf16_t)b.w;
    *((bf16x8*)out + i) = o;
}

// ---------- transpose + cast: W [1024][1024] fp32 [K][N] -> [N][K] bf16 ----------
__global__ __launch_bounds__(256) void transpose_cast(
    const float* __restrict__ W0, const float* __restrict__ W1,
    const float* __restrict__ W2, const float* __restrict__ W3,
    bf16_t* __restrict__ out)
{
    __shared__ float st[32][33];
    const float* W = (blockIdx.z == 0) ? W0 : (blockIdx.z == 1) ? W1
                   : (blockIdx.z == 2) ? W2 : W3;
    bf16_t* o = out + (size_t)blockIdx.z * 1024 * 1024;
    const int n0 = blockIdx.x * 32, k0 = blockIdx.y * 32;
    const int t = threadIdx.x;
    const int r = t >> 3, c4 = (t & 7) * 4;
    float4 v = *(const float4*)(W + (size_t)(k0 + r) * 1024 + n0 + c4);
    st[r][c4 + 0] = v.x; st[r][c4 + 1] = v.y; st[r][c4 + 2] = v.z; st[r][c4 + 3] = v.w;
    __syncthreads();
    bf16_t tmp[4] __attribute__((aligned(8)));
    #pragma unroll
    for (int i = 0; i < 4; ++i) tmp[i] = (bf16_t)st[c4 + i][r];
    *(uint2*)(o + (size_t)(n0 + r) * 1024 + k0 + c4) = *(const uint2*)tmp;
}

// ---------- MFMA GEMM: C = A[M,1024] @ Bt[N,1024]^T + bias ----------
template<bool FUSED, int MT>
__global__ __launch_bounds__(256, 3) void gemm_glds(
    const bf16_t* __restrict__ A, const bf16_t* __restrict__ Bt,
    const float* __restrict__ b0, const float* __restrict__ b1,
    const float* __restrict__ b2,
    bf16_t* __restrict__ Qo, bf16_t* __restrict__ Ko, bf16_t* __restrict__ Vo,
    float* __restrict__ Fo)
{
    const int K = 1024;
    __shared__ __align__(16) bf16_t As[MT * 32];
    __shared__ __align__(16) bf16_t Bs[128 * 32];

    constexpr int NTPW = (MT == 128) ? 4 : 2;
    constexpr int JA   = MT / 64;

    const int tid  = threadIdx.x;
    const int wave = tid >> 6;
    const int lane = tid & 63;
    const int quad = lane >> 4;
    const int l16  = lane & 15;
    const int m0 = blockIdx.y * MT;
    const int n0 = blockIdx.x * 128;
    const int wm = (MT == 128) ? (wave >> 1) * 64 : 0;
    const int wn = (MT == 128) ? (wave & 1) * 64 : wave * 32;

    int goffA[JA], goffB[2];
    #pragma unroll
    for (int j = 0; j < JA; ++j) {
        const int row = j * 64 + (tid >> 2);
        const int cl  = (tid & 3) ^ ((row >> 1) & 3);
        goffA[j] = (m0 + row) * K + cl * 8;
    }
    #pragma unroll
    for (int j = 0; j < 2; ++j) {
        const int row = j * 64 + (tid >> 2);
        const int cl  = (tid & 3) ^ ((row >> 1) & 3);
        goffB[j] = (n0 + row) * K + cl * 8;
    }
    const int ldsoff = wave * 1024;

    f32x4 acc[4][NTPW] = {};
    const int sw = (l16 >> 1) & 3;

    for (int k0 = 0; k0 < K; k0 += 32) {
        #pragma unroll
        for (int j = 0; j < JA; ++j)
            async16(A + goffA[j] + k0, (char*)As + j * 4096 + ldsoff);
        #pragma unroll
        for (int j = 0; j < 2; ++j)
            async16(Bt + goffB[j] + k0, (char*)Bs + j * 4096 + ldsoff);
        __syncthreads();

        bf16x8 af[4], bfr[NTPW];
        #pragma unroll
        for (int mt = 0; mt < 4; ++mt)
            af[mt] = *(const bf16x8*)(&As[(wm + mt * 16 + l16) * 32 + (quad ^ sw) * 8]);
        #pragma unroll
        for (int nt = 0; nt < NTPW; ++nt)
            bfr[nt] = *(const bf16x8*)(&Bs[(wn + nt * 16 + l16) * 32 + (quad ^ sw) * 8]);
        #pragma unroll
        for (int mt = 0; mt < 4; ++mt)
            #pragma unroll
            for (int nt = 0; nt < NTPW; ++nt)
                acc[mt][nt] = __builtin_amdgcn_mfma_f32_16x16x32_bf16(
                    af[mt], bfr[nt], acc[mt][nt], 0, 0, 0);
        __syncthreads();
    }

    if (FUSED) {
        const int sel = n0 >> 10;
        const float* bias = (sel == 0) ? b0 : (sel == 1) ? b1 : b2;
        bf16_t* Cout      = (sel == 0) ? Qo : (sel == 1) ? Ko : Vo;
        const float scl   = (sel == 1) ? SCALE_LOG2E : 1.0f;
        const int nb = n0 & 1023;
        #pragma unroll
        for (int nt = 0; nt < NTPW; ++nt) {
            const int n = nb + wn + nt * 16 + l16;
            const float bb = bias[n];
            #pragma unroll
            for (int mt = 0; mt < 4; ++mt)
                #pragma unroll
                for (int i = 0; i < 4; ++i) {
                    const int m = m0 + wm + mt * 16 + quad * 4 + i;
                    Cout[(size_t)m * 1024 + n] = (bf16_t)((acc[mt][nt][i] + bb) * scl);
                }
        }
    } else {
        #pragma unroll
        for (int nt = 0; nt < NTPW; ++nt) {
            const int n = n0 + wn + nt * 16 + l16;
            const float bb = b0[n];
            #pragma unroll
            for (int mt = 0; mt < 4; ++mt)
                #pragma unroll
                for (int i = 0; i < 4; ++i) {
                    const int m = m0 + wm + mt * 16 + quad * 4 + i;
                    Fo[(size_t)m * 1024 + n] = acc[mt][nt][i] + bb;
                }
        }
    }
}

// ---------- MFMA flash attention, barrier-free main loop ----------
// Grid 1024 (head hd = bx>>2, q-chunk qc = bx&3), 256 thr = 4 waves, wave
// owns 64 q rows (4 q-subs of 16), launch_bounds(256,4) — round-0 work
// partition (proven 57.3us).
// THIS ROUND'S ONE CHANGE: the whole head's V^T (1024 keys x 16 d = 32KB)
// is staged into LDS ONCE up front -> the 16 per-tile __syncthreads and the
// per-tile V staging/double-buffer VANISH from the main loop. Waves run
// fully decoupled for all 16 tiles (round-0 was lockstep-bound: 57us vs
// ~14us pipe floor). 33KB LDS x 4 blocks/CU = 132KB <= 160KB: occupancy
// unchanged. j-loop is `#pragma unroll 1` over 8 iters x 2 static bodies
// (kfA/kfB named double-buffer) so the scheduler can't hoist all 60
// K-prefetch loads into registers at once.
// Compute core byte-identical to round 0: K pre-scaled by 0.125*log2e;
// S^T = K.Q^T via mfma_f32_16x16x32_bf16 (quads 2-3 zero, d=16); C-layout
// of S^T = B-operand layout of v_mfma_f32_16x16x16bf16_1k; p = exp2(s)
// packed (+0x8000, 2 v_perm); Z^T = V^T.P^T, l = 1.P^T; exp =
// __builtin_amdgcn_exp2f (bare v_exp_f32).
// LEDGER: r1/r2/r6 all failed with _1k-QK (+cvt_pk) — arc abandoned.
// r3 (256,8): 64-reg cap -> spill. r4 q-split: FETCH x2 -> slower.
// r5 lgkmcnt-only barrier: fractured scheduling -> slower.
__global__ __launch_bounds__(256, 4) void attn_kernel(
    const bf16_t* __restrict__ Q, const bf16_t* __restrict__ K,
    const bf16_t* __restrict__ V, bf16_t* __restrict__ Z)
{
    __shared__ __align__(16) bf16_t Vt[16][1032];   // V^T whole head, pad->1032

    const int tid  = threadIdx.x;
    const int wave = tid >> 6;
    const int lane = tid & 63;
    const int quad = lane >> 4;
    const int l16  = lane & 15;
    const int hd = blockIdx.x >> 2;
    const int qc = blockIdx.x & 3;
    const int a = hd >> 2, b = hd & 3;
    const int col0 = a * 16;
    const int qbase = qc * 256 + wave * 64;

    // ---- stage full V^T: thread (r=tid>>2, dq=(tid&3)*4) covers keys
    // t*64+r, d dq..dq+3, for t=0..15 ----
    const int r  = tid >> 2;
    const int dq = (tid & 3) * 4;
    const bf16_t* Vp = V + (size_t)(b * 1024 + r) * 1024 + col0 + dq;
    #pragma unroll 4
    for (int t = 0; t < 16; ++t) {
        uint2 vv = *(const uint2*)(Vp + (size_t)(t * 64) * 1024);
        bf16_t t4[4] __attribute__((aligned(8)));
        *(uint2*)t4 = vv;
        #pragma unroll
        for (int ii = 0; ii < 4; ++ii)
            Vt[dq + ii][t * 64 + r] = t4[ii];
    }

    // Q as B-operand of S^T: B[n=q=l16][k=d=quad*8+j], quads 2,3 zero (d<16)
    bf16x8 qf[4] = {};
    if (quad < 2) {
        #pragma unroll
        for (int qs = 0; qs < 4; ++qs)
            qf[qs] = *(const bf16x8*)(Q +
                (size_t)(b * 1024 + qbase + qs * 16 + l16) * 1024 + col0 + quad * 8);
    }

    // K as A-operand of S^T: A[m=key=l16][k=d=quad*8+j], named double-buffer
    const bf16_t* Kp = K + (size_t)(b * 1024 + l16) * 1024 + col0 + quad * 8;
    bf16x8 kfA[4] = {}, kfB[4] = {};
    if (quad < 2) {
        #pragma unroll
        for (int kt = 0; kt < 4; ++kt)
            kfA[kt] = *(const bf16x8*)(Kp + (size_t)(kt * 16) * 1024);
    }

    __syncthreads();   // Vt ready; ONLY barrier in the kernel

    const s16x4 ones = { 0x3F80, 0x3F80, 0x3F80, 0x3F80 };  // bf16 1.0 x4

    f32x4 zacc[4] = {};
    f32x4 lacc[4] = {};

#define ATTN_TILE(JIDX, KFCUR, KFNXT, DO_PREFETCH)                            \
    {                                                                         \
        const int j_ = (JIDX);                                                \
        if (DO_PREFETCH && quad < 2) {                                        \
            _Pragma("unroll")                                                 \
            for (int kt = 0; kt < 4; ++kt)                                    \
                KFNXT[kt] = *(const bf16x8*)(                                 \
                    Kp + (size_t)((j_ + 1) * 64 + kt * 16) * 1024);           \
        }                                                                     \
        _Pragma("unroll")                                                     \
        for (int kt = 0; kt < 4; ++kt) {                                      \
            const s16x4 vfrag = __builtin_bit_cast(s16x4,                     \
                *(const uint2*)(&Vt[l16][j_ * 64 + kt * 16 + quad * 4]));     \
            _Pragma("unroll")                                                 \
            for (int qs = 0; qs < 4; ++qs) {                                  \
                f32x4 zc = {0.f, 0.f, 0.f, 0.f};                              \
                f32x4 s = __builtin_amdgcn_mfma_f32_16x16x32_bf16(            \
                    KFCUR[kt], qf[qs], zc, 0, 0, 0);                          \
                unsigned int u0 = __builtin_bit_cast(unsigned int,            \
                    __builtin_amdgcn_exp2f(s[0])) + 0x8000u;                  \
                unsigned int u1 = __builtin_bit_cast(unsigned int,            \
                    __builtin_amdgcn_exp2f(s[1])) + 0x8000u;                  \
                unsigned int u2 = __builtin_bit_cast(unsigned int,            \
                    __builtin_amdgcn_exp2f(s[2])) + 0x8000u;                  \
                unsigned int u3 = __builtin_bit_cast(unsigned int,            \
                    __builtin_amdgcn_exp2f(s[3])) + 0x8000u;                  \
                uint2 w;                                                      \
                w.x = __builtin_amdgcn_perm(u1, u0, 0x07060302u);             \
                w.y = __builtin_amdgcn_perm(u3, u2, 0x07060302u);             \
                const s16x4 pfrag = __builtin_bit_cast(s16x4, w);             \
                zacc[qs] = __builtin_amdgcn_mfma_f32_16x16x16bf16_1k(         \
                    vfrag, pfrag, zacc[qs], 0, 0, 0);                         \
                lacc[qs] = __builtin_amdgcn_mfma_f32_16x16x16bf16_1k(         \
                    ones, pfrag, lacc[qs], 0, 0, 0);                          \
            }                                                                 \
        }                                                                     \
    }

    #pragma unroll 1
    for (int j2 = 0; j2 < 8; ++j2) {
        ATTN_TILE(2 * j2,     kfA, kfB, true)
        ATTN_TILE(2 * j2 + 1, kfB, kfA, (j2 < 7))
    }
#undef ATTN_TILE

    // epilogue: lane holds Z^T[d=quad*4+i][q=l16] and l[q] in lacc[qs][*]
    #pragma unroll
    for (int qs = 0; qs < 4; ++qs) {
        const float inv = 1.0f / lacc[qs][0];
        const int q = qbase + qs * 16 + l16;
        bf16_t o4[4] __attribute__((aligned(8)));
        #pragma unroll
        for (int i = 0; i < 4; ++i) o4[i] = (bf16_t)(zacc[qs][i] * inv);
        *(uint2*)(Z + ((size_t)hd * 1024 + q) * 16 + quad * 4) = *(const uint2*)o4;
    }
}

extern "C" void kernel_launch(void* const* d_in, const int* in_sizes, int n_in,
                              void* d_out, int out_size, void* d_ws, size_t ws_size,
                              hipStream_t stream) {
    const float* x  = (const float*)d_in[0];
    const float* Wq = (const float*)d_in[1];
    const float* bq = (const float*)d_in[2];
    const float* Wk = (const float*)d_in[3];
    const float* bk = (const float*)d_in[4];
    const float* Wv = (const float*)d_in[5];
    const float* bv = (const float*)d_in[6];
    const float* Wo = (const float*)d_in[7];
    const float* bo = (const float*)d_in[8];
    float* out = (float*)d_out;

    char* ws = (char*)d_ws;
    bf16_t* x_bf = (bf16_t*)(ws);
    bf16_t* Wt   = (bf16_t*)(ws + (8u << 20));   // q|k|v|o slabs, contiguous
    bf16_t* Qb   = (bf16_t*)(ws + (16u << 20));
    bf16_t* Kb   = (bf16_t*)(ws + (24u << 20));
    bf16_t* Vb   = (bf16_t*)(ws + (32u << 20));
    bf16_t* Zb   = (bf16_t*)(ws + (40u << 20));
    bf16_t* WtO  = Wt + (size_t)3 * 1024 * 1024;

    cast_f32_bf16<<<dim3(2048), dim3(256), 0, stream>>>(x, x_bf, 524288);
    transpose_cast<<<dim3(32, 32, 4), dim3(256), 0, stream>>>(Wq, Wk, Wv, Wo, Wt);

    // fused QKV: Bt = [3072][1024] (Wq|Wk|Wv)
    gemm_glds<true, 128><<<dim3(24, 32), dim3(256), 0, stream>>>(
        x_bf, Wt, bq, bk, bv, Qb, Kb, Vb, nullptr);

    attn_kernel<<<dim3(1024), dim3(256), 0, stream>>>(Qb, Kb, Vb, Zb);

    // O-projection: 64x128 tiles -> 512 blocks (2/CU)
    gemm_glds<false, 64><<<dim3(8, 64), dim3(256), 0, stream>>>(
        Zb, WtO, bo, nullptr, nullptr, nullptr, nullptr, nullptr, out);
}

// Round 8
// 191.346 us; speedup vs baseline: 1.4551x; 1.0044x over previous
//
#include <hip/hip_runtime.h>
#include <hip/hip_bf16.h>

// B=4, T=1024, E=1024, ATT=64, NH=16, AH=1024. M = B*T = 4096, K = N = 1024.
// Pipeline: cast x->bf16; transpose+cast W{q,k,v,o} -> [N][K] bf16;
//           fused QKV MFMA GEMM (128x128, global_load_lds, K-slab pre-scaled
//           by 0.125*log2e); register-path MFMA flash attention (S^T trick,
//           HW v_exp_f32, key-split 8-wave); O-proj GEMM (64x128 -> 512 blocks).

typedef __bf16 bf16_t;
typedef bf16_t bf16x8 __attribute__((ext_vector_type(8)));
typedef short  s16x4 __attribute__((ext_vector_type(4)));
typedef float  f32x4 __attribute__((ext_vector_type(4)));

#define SCALE_LOG2E 0.18033688011112042f  /* 0.125 * log2(e) */

__device__ __forceinline__ void async16(const bf16_t* g, void* l) {
    __builtin_amdgcn_global_load_lds(
        (const __attribute__((address_space(1))) unsigned int*)g,
        (__attribute__((address_space(3))) unsigned int*)l,
        16, 0, 0);
}

// ---------- cast fp32 -> bf16, 8 elems/thread ----------
__global__ __launch_bounds__(256) void cast_f32_bf16(
    const float* __restrict__ in, bf16_t* __restrict__ out, int n8)
{
    int i = blockIdx.x * 256 + threadIdx.x;
    if (i >= n8) return;
    const float4* p = (const float4*)in + (size_t)i * 2;
    float4 a = p[0], b = p[1];
    bf16x8 o;
    o[0] = (bf16_t)a.x; o[1] = (bf16_t)a.y; o[2] = (bf16_t)a.z; o[3] = (bf16_t)a.w;
    o[4] = (bf16_t)b.x; o[5] = (bf16_t)b.y; o[6] = (bf16_t)b.z; o[7] = (bf16_t)b.w;
    *((bf16x8*)out + i) = o;
}

// ---------- transpose + cast: W [1024][1024] fp32 [K][N] -> [N][K] bf16 ----------
__global__ __launch_bounds__(256) void transpose_cast(
    const float* __restrict__ W0, const float* __restrict__ W1,
    const float* __restrict__ W2, const float* __restrict__ W3,
    bf16_t* __restrict__ out)
{
    __shared__ float st[32][33];
    const float* W = (blockIdx.z == 0) ? W0 : (blockIdx.z == 1) ? W1
                   : (blockIdx.z == 2) ? W2 : W3;
    bf16_t* o = out + (size_t)blockIdx.z * 1024 * 1024;
    const int n0 = blockIdx.x * 32, k0 = blockIdx.y * 32;
    const int t = threadIdx.x;
    const int r = t >> 3, c4 = (t & 7) * 4;
    float4 v = *(const float4*)(W + (size_t)(k0 + r) * 1024 + n0 + c4);
    st[r][c4 + 0] = v.x; st[r][c4 + 1] = v.y; st[r][c4 + 2] = v.z; st[r][c4 + 3] = v.w;
    __syncthreads();
    bf16_t tmp[4] __attribute__((aligned(8)));
    #pragma unroll
    for (int i = 0; i < 4; ++i) tmp[i] = (bf16_t)st[c4 + i][r];
    *(uint2*)(o + (size_t)(n0 + r) * 1024 + k0 + c4) = *(const uint2*)tmp;
}

// ---------- MFMA GEMM: C = A[M,1024] @ Bt[N,1024]^T + bias ----------
template<bool FUSED, int MT>
__global__ __launch_bounds__(256, 3) void gemm_glds(
    const bf16_t* __restrict__ A, const bf16_t* __restrict__ Bt,
    const float* __restrict__ b0, const float* __restrict__ b1,
    const float* __restrict__ b2,
    bf16_t* __restrict__ Qo, bf16_t* __restrict__ Ko, bf16_t* __restrict__ Vo,
    float* __restrict__ Fo)
{
    const int K = 1024;
    __shared__ __align__(16) bf16_t As[MT * 32];
    __shared__ __align__(16) bf16_t Bs[128 * 32];

    constexpr int NTPW = (MT == 128) ? 4 : 2;
    constexpr int JA   = MT / 64;

    const int tid  = threadIdx.x;
    const int wave = tid >> 6;
    const int lane = tid & 63;
    const int quad = lane >> 4;
    const int l16  = lane & 15;
    const int m0 = blockIdx.y * MT;
    const int n0 = blockIdx.x * 128;
    const int wm = (MT == 128) ? (wave >> 1) * 64 : 0;
    const int wn = (MT == 128) ? (wave & 1) * 64 : wave * 32;

    int goffA[JA], goffB[2];
    #pragma unroll
    for (int j = 0; j < JA; ++j) {
        const int row = j * 64 + (tid >> 2);
        const int cl  = (tid & 3) ^ ((row >> 1) & 3);
        goffA[j] = (m0 + row) * K + cl * 8;
    }
    #pragma unroll
    for (int j = 0; j < 2; ++j) {
        const int row = j * 64 + (tid >> 2);
        const int cl  = (tid & 3) ^ ((row >> 1) & 3);
        goffB[j] = (n0 + row) * K + cl * 8;
    }
    const int ldsoff = wave * 1024;

    f32x4 acc[4][NTPW] = {};
    const int sw = (l16 >> 1) & 3;

    for (int k0 = 0; k0 < K; k0 += 32) {
        #pragma unroll
        for (int j = 0; j < JA; ++j)
            async16(A + goffA[j] + k0, (char*)As + j * 4096 + ldsoff);
        #pragma unroll
        for (int j = 0; j < 2; ++j)
            async16(Bt + goffB[j] + k0, (char*)Bs + j * 4096 + ldsoff);
        __syncthreads();

        bf16x8 af[4], bfr[NTPW];
        #pragma unroll
        for (int mt = 0; mt < 4; ++mt)
            af[mt] = *(const bf16x8*)(&As[(wm + mt * 16 + l16) * 32 + (quad ^ sw) * 8]);
        #pragma unroll
        for (int nt = 0; nt < NTPW; ++nt)
            bfr[nt] = *(const bf16x8*)(&Bs[(wn + nt * 16 + l16) * 32 + (quad ^ sw) * 8]);
        #pragma unroll
        for (int mt = 0; mt < 4; ++mt)
            #pragma unroll
            for (int nt = 0; nt < NTPW; ++nt)
                acc[mt][nt] = __builtin_amdgcn_mfma_f32_16x16x32_bf16(
                    af[mt], bfr[nt], acc[mt][nt], 0, 0, 0);
        __syncthreads();
    }

    if (FUSED) {
        const int sel = n0 >> 10;
        const float* bias = (sel == 0) ? b0 : (sel == 1) ? b1 : b2;
        bf16_t* Cout      = (sel == 0) ? Qo : (sel == 1) ? Ko : Vo;
        const float scl   = (sel == 1) ? SCALE_LOG2E : 1.0f;
        const int nb = n0 & 1023;
        #pragma unroll
        for (int nt = 0; nt < NTPW; ++nt) {
            const int n = nb + wn + nt * 16 + l16;
            const float bb = bias[n];
            #pragma unroll
            for (int mt = 0; mt < 4; ++mt)
                #pragma unroll
                for (int i = 0; i < 4; ++i) {
                    const int m = m0 + wm + mt * 16 + quad * 4 + i;
                    Cout[(size_t)m * 1024 + n] = (bf16_t)((acc[mt][nt][i] + bb) * scl);
                }
        }
    } else {
        #pragma unroll
        for (int nt = 0; nt < NTPW; ++nt) {
            const int n = n0 + wn + nt * 16 + l16;
            const float bb = b0[n];
            #pragma unroll
            for (int mt = 0; mt < 4; ++mt)
                #pragma unroll
                for (int i = 0; i < 4; ++i) {
                    const int m = m0 + wm + mt * 16 + quad * 4 + i;
                    Fo[(size_t)m * 1024 + n] = acc[mt][nt][i] + bb;
                }
        }
    }
}

// ---------- MFMA flash attention, key-split 8-wave ----------
// Grid 1024 (head hd = bx>>2, q-chunk qc = bx&3), 512 thr = 8 waves.
// THIS ROUND'S ONE CHANGE: key-split. Waves 0-3 own q-subs x key tiles 0-7;
// waves 4-7 own the SAME q rows x key tiles 8-15. p = exp2(s) has NO
// running max, so partials combine by pure addition: Z = Z_lo + Z_hi,
// l = l_lo + l_hi (through LDS, reusing the dead Vt buffer). This doubles
// residency (16 -> 32 waves/CU: LDS 33KB x 4 blocks, VGPR ~56 <= 64) at
// CONSTANT total issue work and CONSTANT K/V HBM traffic — unlike r4's
// q-split, which duplicated the K-prefetch stream (FETCH x2 -> slower).
// launch_bounds(512,4): cap 128 regs (r3 lesson: never cap below live
// state); actual residency comes from real VGPR (~56) and LDS.
// Main-loop structure per wave = r7's barrier-free loop over 8 tiles:
// kfA/kfB named K double-buffer, #pragma unroll 1 over j2, full-head V^T
// staged once (one barrier), no per-tile barriers.
// Compute core byte-identical to r0/r7: K pre-scaled by 0.125*log2e;
// S^T = K.Q^T via mfma_f32_16x16x32_bf16 (quads 2-3 zero, d=16); C-layout
// of S^T = B-operand layout of v_mfma_f32_16x16x16bf16_1k; p = exp2(s)
// packed (+0x8000, 2 v_perm); Z^T = V^T.P^T, l = 1.P^T; exp =
// __builtin_amdgcn_exp2f (bare v_exp_f32).
// LEDGER: r1/r2/r6 failed with _1k-QK(+cvt_pk) — arc abandoned. r3 (256,8)
// reg-cap spill. r4 q-split FETCH x2. r5 lgkmcnt-barrier fractured sched.
// r7 barrier-free: only -2us -> stall is in-wave latency, hence this round.
__global__ __launch_bounds__(512, 4) void attn_kernel(
    const bf16_t* __restrict__ Q, const bf16_t* __restrict__ K,
    const bf16_t* __restrict__ V, bf16_t* __restrict__ Z)
{
    // 33 KB: V^T [16][1032] during main loop; f32 combine area afterwards.
    __shared__ __align__(16) char smem[16 * 1032 * 2];
    bf16_t (*Vt)[1032] = (bf16_t (*)[1032])smem;
    float* cmb = (float*)smem;     // [4 waves][64 lanes][21]; 21.5 KB

    const int tid  = threadIdx.x;
    const int wave = tid >> 6;        // 0..7
    const int lane = tid & 63;
    const int quad = lane >> 4;
    const int l16  = lane & 15;
    const int hd = blockIdx.x >> 2;
    const int qc = blockIdx.x & 3;
    const int a = hd >> 2, b = hd & 3;
    const int col0 = a * 16;
    const int qw   = wave & 3;        // q-wave id within half
    const int kvh  = wave >> 2;       // key half 0/1
    const int qbase = qc * 256 + qw * 64;
    const int kb512 = kvh * 512;      // this wave's key-range base

    // ---- stage full V^T with 512 threads: thread (r=tid>>2 in 0..127,
    // dq=(tid&3)*4) covers keys r+128t (t=0..7), d dq..dq+3 ----
    const int r  = tid >> 2;
    const int dq = (tid & 3) * 4;
    const bf16_t* Vp = V + (size_t)(b * 1024 + r) * 1024 + col0 + dq;
    #pragma unroll 2
    for (int t = 0; t < 8; ++t) {
        uint2 vv = *(const uint2*)(Vp + (size_t)(t * 128) * 1024);
        bf16_t t4[4] __attribute__((aligned(8)));
        *(uint2*)t4 = vv;
        #pragma unroll
        for (int ii = 0; ii < 4; ++ii)
            Vt[dq + ii][t * 128 + r] = t4[ii];
    }

    // Q as B-operand of S^T: B[n=q=l16][k=d=quad*8+j], quads 2,3 zero (d<16)
    bf16x8 qf[4] = {};
    if (quad < 2) {
        #pragma unroll
        for (int qs = 0; qs < 4; ++qs)
            qf[qs] = *(const bf16x8*)(Q +
                (size_t)(b * 1024 + qbase + qs * 16 + l16) * 1024 + col0 + quad * 8);
    }

    // K for this wave's key half: A[m=key=l16][k=d=quad*8+j], named dbuf
    const bf16_t* Kp = K + (size_t)(b * 1024 + kb512 + l16) * 1024 + col0 + quad * 8;
    bf16x8 kfA[4] = {}, kfB[4] = {};
    if (quad < 2) {
        #pragma unroll
        for (int kt = 0; kt < 4; ++kt)
            kfA[kt] = *(const bf16x8*)(Kp + (size_t)(kt * 16) * 1024);
    }

    __syncthreads();   // Vt ready

    const s16x4 ones = { 0x3F80, 0x3F80, 0x3F80, 0x3F80 };  // bf16 1.0 x4

    f32x4 zacc[4] = {};
    f32x4 lacc[4] = {};

#define ATTN_TILE(JIDX, KFCUR, KFNXT, DO_PREFETCH)                            \
    {                                                                         \
        const int j_ = (JIDX);                                                \
        if (DO_PREFETCH && quad < 2) {                                        \
            _Pragma("unroll")                                                 \
            for (int kt = 0; kt < 4; ++kt)                                    \
                KFNXT[kt] = *(const bf16x8*)(                                 \
                    Kp + (size_t)((j_ + 1) * 64 + kt * 16) * 1024);           \
        }                                                                     \
        _Pragma("unroll")                                                     \
        for (int kt = 0; kt < 4; ++kt) {                                      \
            const s16x4 vfrag = __builtin_bit_cast(s16x4,                     \
                *(const uint2*)(&Vt[l16][kb512 + j_ * 64 + kt * 16 + quad * 4])); \
            _Pragma("unroll")                                                 \
            for (int qs = 0; qs < 4; ++qs) {                                  \
                f32x4 zc = {0.f, 0.f, 0.f, 0.f};                              \
                f32x4 s = __builtin_amdgcn_mfma_f32_16x16x32_bf16(            \
                    KFCUR[kt], qf[qs], zc, 0, 0, 0);                          \
                unsigned int u0 = __builtin_bit_cast(unsigned int,            \
                    __builtin_amdgcn_exp2f(s[0])) + 0x8000u;                  \
                unsigned int u1 = __builtin_bit_cast(unsigned int,            \
                    __builtin_amdgcn_exp2f(s[1])) + 0x8000u;                  \
                unsigned int u2 = __builtin_bit_cast(unsigned int,            \
                    __builtin_amdgcn_exp2f(s[2])) + 0x8000u;                  \
                unsigned int u3 = __builtin_bit_cast(unsigned int,            \
                    __builtin_amdgcn_exp2f(s[3])) + 0x8000u;                  \
                uint2 w;                                                      \
                w.x = __builtin_amdgcn_perm(u1, u0, 0x07060302u);             \
                w.y = __builtin_amdgcn_perm(u3, u2, 0x07060302u);             \
                const s16x4 pfrag = __builtin_bit_cast(s16x4, w);             \
                zacc[qs] = __builtin_amdgcn_mfma_f32_16x16x16bf16_1k(         \
                    vfrag, pfrag, zacc[qs], 0, 0, 0);                         \
                lacc[qs] = __builtin_amdgcn_mfma_f32_16x16x16bf16_1k(         \
                    ones, pfrag, lacc[qs], 0, 0, 0);                          \
            }                                                                 \
        }                                                                     \
    }

    #pragma unroll 1
    for (int j2 = 0; j2 < 4; ++j2) {
        ATTN_TILE(2 * j2,     kfA, kfB, true)
        ATTN_TILE(2 * j2 + 1, kfB, kfA, (j2 < 3))
    }
#undef ATTN_TILE

    // ---- combine key halves: waves 4-7 publish partials via LDS (Vt dead)
    __syncthreads();
    if (wave >= 4) {
        float* p = cmb + ((size_t)((wave - 4) * 64 + lane)) * 21;
        #pragma unroll
        for (int qs = 0; qs < 4; ++qs) {
            #pragma unroll
            for (int i = 0; i < 4; ++i) p[qs * 4 + i] = zacc[qs][i];
            p[16 + qs] = lacc[qs][0];
        }
    }
    __syncthreads();
    if (wave < 4) {
        const float* p = cmb + ((size_t)(wave * 64 + lane)) * 21;
        #pragma unroll
        for (int qs = 0; qs < 4; ++qs) {
            const float inv = 1.0f / (lacc[qs][0] + p[16 + qs]);
            const int q = qbase + qs * 16 + l16;
            bf16_t o4[4] __attribute__((aligned(8)));
            #pragma unroll
            for (int i = 0; i < 4; ++i)
                o4[i] = (bf16_t)((zacc[qs][i] + p[qs * 4 + i]) * inv);
            *(uint2*)(Z + ((size_t)hd * 1024 + q) * 16 + quad * 4) = *(const uint2*)o4;
        }
    }
}

extern "C" void kernel_launch(void* const* d_in, const int* in_sizes, int n_in,
                              void* d_out, int out_size, void* d_ws, size_t ws_size,
                              hipStream_t stream) {
    const float* x  = (const float*)d_in[0];
    const float* Wq = (const float*)d_in[1];
    const float* bq = (const float*)d_in[2];
    const float* Wk = (const float*)d_in[3];
    const float* bk = (const float*)d_in[4];
    const float* Wv = (const float*)d_in[5];
    const float* bv = (const float*)d_in[6];
    const float* Wo = (const float*)d_in[7];
    const float* bo = (const float*)d_in[8];
    float* out = (float*)d_out;

    char* ws = (char*)d_ws;
    bf16_t* x_bf = (bf16_t*)(ws);
    bf16_t* Wt   = (bf16_t*)(ws + (8u << 20));   // q|k|v|o slabs, contiguous
    bf16_t* Qb   = (bf16_t*)(ws + (16u << 20));
    bf16_t* Kb   = (bf16_t*)(ws + (24u << 20));
    bf16_t* Vb   = (bf16_t*)(ws + (32u << 20));
    bf16_t* Zb   = (bf16_t*)(ws + (40u << 20));
    bf16_t* WtO  = Wt + (size_t)3 * 1024 * 1024;

    cast_f32_bf16<<<dim3(2048), dim3(256), 0, stream>>>(x, x_bf, 524288);
    transpose_cast<<<dim3(32, 32, 4), dim3(256), 0, stream>>>(Wq, Wk, Wv, Wo, Wt);

    // fused QKV: Bt = [3072][1024] (Wq|Wk|Wv)
    gemm_glds<true, 128><<<dim3(24, 32), dim3(256), 0, stream>>>(
        x_bf, Wt, bq, bk, bv, Qb, Kb, Vb, nullptr);

    attn_kernel<<<dim3(1024), dim3(512), 0, stream>>>(Qb, Kb, Vb, Zb);

    // O-projection: 64x128 tiles -> 512 blocks (2/CU)
    gemm_glds<false, 64><<<dim3(8, 64), dim3(256), 0, stream>>>(
        Zb, WtO, bo, nullptr, nullptr, nullptr, nullptr, nullptr, out);
}

// Round 9
// 188.117 us; speedup vs baseline: 1.4800x; 1.0172x over previous
//
#include <hip/hip_runtime.h>
#include <hip/hip_bf16.h>

// B=4, T=1024, E=1024, ATT=64, NH=16, AH=1024. M = B*T = 4096, K = N = 1024.
// Pipeline: cast x->bf16; transpose+cast W{q,k,v,o} -> [N][K] bf16;
//           fused QKV MFMA GEMM (128x128, BK=64, global_load_lds, K-slab
//           pre-scaled by 0.125*log2e); register-path MFMA flash attention
//           (S^T trick, HW v_exp_f32, key-split 8-wave); O-proj GEMM.

typedef __bf16 bf16_t;
typedef bf16_t bf16x8 __attribute__((ext_vector_type(8)));
typedef short  s16x4 __attribute__((ext_vector_type(4)));
typedef float  f32x4 __attribute__((ext_vector_type(4)));

#define SCALE_LOG2E 0.18033688011112042f  /* 0.125 * log2(e) */

__device__ __forceinline__ void async16(const bf16_t* g, void* l) {
    __builtin_amdgcn_global_load_lds(
        (const __attribute__((address_space(1))) unsigned int*)g,
        (__attribute__((address_space(3))) unsigned int*)l,
        16, 0, 0);
}

// ---------- cast fp32 -> bf16, 8 elems/thread ----------
__global__ __launch_bounds__(256) void cast_f32_bf16(
    const float* __restrict__ in, bf16_t* __restrict__ out, int n8)
{
    int i = blockIdx.x * 256 + threadIdx.x;
    if (i >= n8) return;
    const float4* p = (const float4*)in + (size_t)i * 2;
    float4 a = p[0], b = p[1];
    bf16x8 o;
    o[0] = (bf16_t)a.x; o[1] = (bf16_t)a.y; o[2] = (bf16_t)a.z; o[3] = (bf16_t)a.w;
    o[4] = (bf16_t)b.x; o[5] = (bf16_t)b.y; o[6] = (bf16_t)b.z; o[7] = (bf16_t)b.w;
    *((bf16x8*)out + i) = o;
}

// ---------- transpose + cast: W [1024][1024] fp32 [K][N] -> [N][K] bf16 ----------
__global__ __launch_bounds__(256) void transpose_cast(
    const float* __restrict__ W0, const float* __restrict__ W1,
    const float* __restrict__ W2, const float* __restrict__ W3,
    bf16_t* __restrict__ out)
{
    __shared__ float st[32][33];
    const float* W = (blockIdx.z == 0) ? W0 : (blockIdx.z == 1) ? W1
                   : (blockIdx.z == 2) ? W2 : W3;
    bf16_t* o = out + (size_t)blockIdx.z * 1024 * 1024;
    const int n0 = blockIdx.x * 32, k0 = blockIdx.y * 32;
    const int t = threadIdx.x;
    const int r = t >> 3, c4 = (t & 7) * 4;
    float4 v = *(const float4*)(W + (size_t)(k0 + r) * 1024 + n0 + c4);
    st[r][c4 + 0] = v.x; st[r][c4 + 1] = v.y; st[r][c4 + 2] = v.z; st[r][c4 + 3] = v.w;
    __syncthreads();
    bf16_t tmp[4] __attribute__((aligned(8)));
    #pragma unroll
    for (int i = 0; i < 4; ++i) tmp[i] = (bf16_t)st[c4 + i][r];
    *(uint2*)(o + (size_t)(n0 + r) * 1024 + k0 + c4) = *(const uint2*)tmp;
}

// ---------- MFMA GEMM: C = A[M,1024] @ Bt[N,1024]^T + bias ----------
// THIS ROUND: BK=64 (two 32-wide slabs per LDS buffer, staged together,
// computed together). Halves barrier count (64 -> 32 per block): each
// __syncthreads drains the global_load_lds vmcnt queue (the m97-structure
// ~20% stall), so fewer drains with 2x MFMA amortized per drain. LDS
// 16->32KB (MT=128): 3 blocks/CU x 32KB = 96KB <= 160KB, occupancy
// unchanged. Pre-swizzled-global / linear-LDS staging algebra is per-slab
// identical to the proven BK=32 version (slab = +32 global cols, +MT*64B
// LDS offset).
template<bool FUSED, int MT>
__global__ __launch_bounds__(256, 3) void gemm_glds(
    const bf16_t* __restrict__ A, const bf16_t* __restrict__ Bt,
    const float* __restrict__ b0, const float* __restrict__ b1,
    const float* __restrict__ b2,
    bf16_t* __restrict__ Qo, bf16_t* __restrict__ Ko, bf16_t* __restrict__ Vo,
    float* __restrict__ Fo)
{
    const int K = 1024;
    __shared__ __align__(16) bf16_t As[2 * MT * 32];
    __shared__ __align__(16) bf16_t Bs[2 * 128 * 32];

    constexpr int NTPW = (MT == 128) ? 4 : 2;
    constexpr int JA   = MT / 64;

    const int tid  = threadIdx.x;
    const int wave = tid >> 6;
    const int lane = tid & 63;
    const int quad = lane >> 4;
    const int l16  = lane & 15;
    const int m0 = blockIdx.y * MT;
    const int n0 = blockIdx.x * 128;
    const int wm = (MT == 128) ? (wave >> 1) * 64 : 0;
    const int wn = (MT == 128) ? (wave & 1) * 64 : wave * 32;

    int goffA[JA], goffB[2];
    #pragma unroll
    for (int j = 0; j < JA; ++j) {
        const int row = j * 64 + (tid >> 2);
        const int cl  = (tid & 3) ^ ((row >> 1) & 3);
        goffA[j] = (m0 + row) * K + cl * 8;
    }
    #pragma unroll
    for (int j = 0; j < 2; ++j) {
        const int row = j * 64 + (tid >> 2);
        const int cl  = (tid & 3) ^ ((row >> 1) & 3);
        goffB[j] = (n0 + row) * K + cl * 8;
    }
    const int ldsoff = wave * 1024;

    f32x4 acc[4][NTPW] = {};
    const int sw = (l16 >> 1) & 3;

    for (int k0 = 0; k0 < K; k0 += 64) {
        #pragma unroll
        for (int s = 0; s < 2; ++s) {
            #pragma unroll
            for (int j = 0; j < JA; ++j)
                async16(A + goffA[j] + k0 + s * 32,
                        (char*)As + s * (MT * 64) + j * 4096 + ldsoff);
            #pragma unroll
            for (int j = 0; j < 2; ++j)
                async16(Bt + goffB[j] + k0 + s * 32,
                        (char*)Bs + s * 8192 + j * 4096 + ldsoff);
        }
        __syncthreads();

        #pragma unroll
        for (int s = 0; s < 2; ++s) {
            bf16x8 af[4], bfr[NTPW];
            #pragma unroll
            for (int mt = 0; mt < 4; ++mt)
                af[mt] = *(const bf16x8*)(&As[s * (MT * 32) +
                    (wm + mt * 16 + l16) * 32 + (quad ^ sw) * 8]);
            #pragma unroll
            for (int nt = 0; nt < NTPW; ++nt)
                bfr[nt] = *(const bf16x8*)(&Bs[s * (128 * 32) +
                    (wn + nt * 16 + l16) * 32 + (quad ^ sw) * 8]);
            #pragma unroll
            for (int mt = 0; mt < 4; ++mt)
                #pragma unroll
                for (int nt = 0; nt < NTPW; ++nt)
                    acc[mt][nt] = __builtin_amdgcn_mfma_f32_16x16x32_bf16(
                        af[mt], bfr[nt], acc[mt][nt], 0, 0, 0);
        }
        __syncthreads();
    }

    if (FUSED) {
        const int sel = n0 >> 10;
        const float* bias = (sel == 0) ? b0 : (sel == 1) ? b1 : b2;
        bf16_t* Cout      = (sel == 0) ? Qo : (sel == 1) ? Ko : Vo;
        const float scl   = (sel == 1) ? SCALE_LOG2E : 1.0f;
        const int nb = n0 & 1023;
        #pragma unroll
        for (int nt = 0; nt < NTPW; ++nt) {
            const int n = nb + wn + nt * 16 + l16;
            const float bb = bias[n];
            #pragma unroll
            for (int mt = 0; mt < 4; ++mt)
                #pragma unroll
                for (int i = 0; i < 4; ++i) {
                    const int m = m0 + wm + mt * 16 + quad * 4 + i;
                    Cout[(size_t)m * 1024 + n] = (bf16_t)((acc[mt][nt][i] + bb) * scl);
                }
        }
    } else {
        #pragma unroll
        for (int nt = 0; nt < NTPW; ++nt) {
            const int n = n0 + wn + nt * 16 + l16;
            const float bb = b0[n];
            #pragma unroll
            for (int mt = 0; mt < 4; ++mt)
                #pragma unroll
                for (int i = 0; i < 4; ++i) {
                    const int m = m0 + wm + mt * 16 + quad * 4 + i;
                    Fo[(size_t)m * 1024 + n] = acc[mt][nt][i] + bb;
                }
        }
    }
}

// ---------- MFMA flash attention, key-split 8-wave (UNCHANGED from r8) ----------
// Grid 1024 (head hd = bx>>2, q-chunk qc = bx&3), 512 thr = 8 waves.
// Waves 0-3: key tiles 0-7; waves 4-7: same q rows, key tiles 8-15;
// partials combine additively via LDS (no running max in this softmax).
// Full-head V^T staged once; barrier-free main loop; kfA/kfB named K dbuf.
// Core: K pre-scaled by 0.125*log2e; S^T = K.Q^T via mfma_f32_16x16x32_bf16
// (quads 2-3 zero, d=16); p = exp2(s) packed (+0x8000, 2 v_perm);
// Z^T = V^T.P^T, l = 1.P^T via _1k; exp = bare v_exp_f32.
// LEDGER: r1/r2/r6 failed with _1k-QK(+cvt_pk) — abandoned. r3 reg-cap
// spill. r4 q-split FETCH x2. r5 asm barrier fractured sched. r7 barrier
// removal -2us, r8 key-split -1.5us: attn is dependency-latency-bound at
// ~54us; parked. Counters r8: Mfma 38, VALU 60, HBM 10%.
__global__ __launch_bounds__(512, 4) void attn_kernel(
    const bf16_t* __restrict__ Q, const bf16_t* __restrict__ K,
    const bf16_t* __restrict__ V, bf16_t* __restrict__ Z)
{
    __shared__ __align__(16) char smem[16 * 1032 * 2];
    bf16_t (*Vt)[1032] = (bf16_t (*)[1032])smem;
    float* cmb = (float*)smem;     // [4 waves][64 lanes][21]

    const int tid  = threadIdx.x;
    const int wave = tid >> 6;        // 0..7
    const int lane = tid & 63;
    const int quad = lane >> 4;
    const int l16  = lane & 15;
    const int hd = blockIdx.x >> 2;
    const int qc = blockIdx.x & 3;
    const int a = hd >> 2, b = hd & 3;
    const int col0 = a * 16;
    const int qw   = wave & 3;
    const int kvh  = wave >> 2;
    const int qbase = qc * 256 + qw * 64;
    const int kb512 = kvh * 512;

    const int r  = tid >> 2;
    const int dq = (tid & 3) * 4;
    const bf16_t* Vp = V + (size_t)(b * 1024 + r) * 1024 + col0 + dq;
    #pragma unroll 2
    for (int t = 0; t < 8; ++t) {
        uint2 vv = *(const uint2*)(Vp + (size_t)(t * 128) * 1024);
        bf16_t t4[4] __attribute__((aligned(8)));
        *(uint2*)t4 = vv;
        #pragma unroll
        for (int ii = 0; ii < 4; ++ii)
            Vt[dq + ii][t * 128 + r] = t4[ii];
    }

    bf16x8 qf[4] = {};
    if (quad < 2) {
        #pragma unroll
        for (int qs = 0; qs < 4; ++qs)
            qf[qs] = *(const bf16x8*)(Q +
                (size_t)(b * 1024 + qbase + qs * 16 + l16) * 1024 + col0 + quad * 8);
    }

    const bf16_t* Kp = K + (size_t)(b * 1024 + kb512 + l16) * 1024 + col0 + quad * 8;
    bf16x8 kfA[4] = {}, kfB[4] = {};
    if (quad < 2) {
        #pragma unroll
        for (int kt = 0; kt < 4; ++kt)
            kfA[kt] = *(const bf16x8*)(Kp + (size_t)(kt * 16) * 1024);
    }

    __syncthreads();   // Vt ready

    const s16x4 ones = { 0x3F80, 0x3F80, 0x3F80, 0x3F80 };  // bf16 1.0 x4

    f32x4 zacc[4] = {};
    f32x4 lacc[4] = {};

#define ATTN_TILE(JIDX, KFCUR, KFNXT, DO_PREFETCH)                            \
    {                                                                         \
        const int j_ = (JIDX);                                                \
        if (DO_PREFETCH && quad < 2) {                                        \
            _Pragma("unroll")                                                 \
            for (int kt = 0; kt < 4; ++kt)                                    \
                KFNXT[kt] = *(const bf16x8*)(                                 \
                    Kp + (size_t)((j_ + 1) * 64 + kt * 16) * 1024);           \
        }                                                                     \
        _Pragma("unroll")                                                     \
        for (int kt = 0; kt < 4; ++kt) {                                      \
            const s16x4 vfrag = __builtin_bit_cast(s16x4,                     \
                *(const uint2*)(&Vt[l16][kb512 + j_ * 64 + kt * 16 + quad * 4])); \
            _Pragma("unroll")                                                 \
            for (int qs = 0; qs < 4; ++qs) {                                  \
                f32x4 zc = {0.f, 0.f, 0.f, 0.f};                              \
                f32x4 s = __builtin_amdgcn_mfma_f32_16x16x32_bf16(            \
                    KFCUR[kt], qf[qs], zc, 0, 0, 0);                          \
                unsigned int u0 = __builtin_bit_cast(unsigned int,            \
                    __builtin_amdgcn_exp2f(s[0])) + 0x8000u;                  \
                unsigned int u1 = __builtin_bit_cast(unsigned int,            \
                    __builtin_amdgcn_exp2f(s[1])) + 0x8000u;                  \
                unsigned int u2 = __builtin_bit_cast(unsigned int,            \
                    __builtin_amdgcn_exp2f(s[2])) + 0x8000u;                  \
                unsigned int u3 = __builtin_bit_cast(unsigned int,            \
                    __builtin_amdgcn_exp2f(s[3])) + 0x8000u;                  \
                uint2 w;                                                      \
                w.x = __builtin_amdgcn_perm(u1, u0, 0x07060302u);             \
                w.y = __builtin_amdgcn_perm(u3, u2, 0x07060302u);             \
                const s16x4 pfrag = __builtin_bit_cast(s16x4, w);             \
                zacc[qs] = __builtin_amdgcn_mfma_f32_16x16x16bf16_1k(         \
                    vfrag, pfrag, zacc[qs], 0, 0, 0);                         \
                lacc[qs] = __builtin_amdgcn_mfma_f32_16x16x16bf16_1k(         \
                    ones, pfrag, lacc[qs], 0, 0, 0);                          \
            }                                                                 \
        }                                                                     \
    }

    #pragma unroll 1
    for (int j2 = 0; j2 < 4; ++j2) {
        ATTN_TILE(2 * j2,     kfA, kfB, true)
        ATTN_TILE(2 * j2 + 1, kfB, kfA, (j2 < 3))
    }
#undef ATTN_TILE

    __syncthreads();
    if (wave >= 4) {
        float* p = cmb + ((size_t)((wave - 4) * 64 + lane)) * 21;
        #pragma unroll
        for (int qs = 0; qs < 4; ++qs) {
            #pragma unroll
            for (int i = 0; i < 4; ++i) p[qs * 4 + i] = zacc[qs][i];
            p[16 + qs] = lacc[qs][0];
        }
    }
    __syncthreads();
    if (wave < 4) {
        const float* p = cmb + ((size_t)(wave * 64 + lane)) * 21;
        #pragma unroll
        for (int qs = 0; qs < 4; ++qs) {
            const float inv = 1.0f / (lacc[qs][0] + p[16 + qs]);
            const int q = qbase + qs * 16 + l16;
            bf16_t o4[4] __attribute__((aligned(8)));
            #pragma unroll
            for (int i = 0; i < 4; ++i)
                o4[i] = (bf16_t)((zacc[qs][i] + p[qs * 4 + i]) * inv);
            *(uint2*)(Z + ((size_t)hd * 1024 + q) * 16 + quad * 4) = *(const uint2*)o4;
        }
    }
}

extern "C" void kernel_launch(void* const* d_in, const int* in_sizes, int n_in,
                              void* d_out, int out_size, void* d_ws, size_t ws_size,
                              hipStream_t stream) {
    const float* x  = (const float*)d_in[0];
    const float* Wq = (const float*)d_in[1];
    const float* bq = (const float*)d_in[2];
    const float* Wk = (const float*)d_in[3];
    const float* bk = (const float*)d_in[4];
    const float* Wv = (const float*)d_in[5];
    const float* bv = (const float*)d_in[6];
    const float* Wo = (const float*)d_in[7];
    const float* bo = (const float*)d_in[8];
    float* out = (float*)d_out;

    char* ws = (char*)d_ws;
    bf16_t* x_bf = (bf16_t*)(ws);
    bf16_t* Wt   = (bf16_t*)(ws + (8u << 20));   // q|k|v|o slabs, contiguous
    bf16_t* Qb   = (bf16_t*)(ws + (16u << 20));
    bf16_t* Kb   = (bf16_t*)(ws + (24u << 20));
    bf16_t* Vb   = (bf16_t*)(ws + (32u << 20));
    bf16_t* Zb   = (bf16_t*)(ws + (40u << 20));
    bf16_t* WtO  = Wt + (size_t)3 * 1024 * 1024;

    cast_f32_bf16<<<dim3(2048), dim3(256), 0, stream>>>(x, x_bf, 524288);
    transpose_cast<<<dim3(32, 32, 4), dim3(256), 0, stream>>>(Wq, Wk, Wv, Wo, Wt);

    // fused QKV: Bt = [3072][1024] (Wq|Wk|Wv)
    gemm_glds<true, 128><<<dim3(24, 32), dim3(256), 0, stream>>>(
        x_bf, Wt, bq, bk, bv, Qb, Kb, Vb, nullptr);

    attn_kernel<<<dim3(1024), dim3(512), 0, stream>>>(Qb, Kb, Vb, Zb);

    // O-projection: 64x128 tiles -> 512 blocks (2/CU)
    gemm_glds<false, 64><<<dim3(8, 64), dim3(256), 0, stream>>>(
        Zb, WtO, bo, nullptr, nullptr, nullptr, nullptr, nullptr, out);
}

// Round 11
// 186.787 us; speedup vs baseline: 1.4906x; 1.0071x over previous
//
#include <hip/hip_runtime.h>
#include <hip/hip_bf16.h>

// B=4, T=1024, E=1024, ATT=64, NH=16, AH=1024. M = B*T = 4096, K = N = 1024.
// Pipeline: cast x->bf16; transpose+cast W{q,k,v,o} -> [N][K] bf16;
//           fused QKV MFMA GEMM (128x128, BK=64, global_load_lds, K-slab
//           pre-scaled by 0.125*log2e); register-path MFMA flash attention
//           (S^T trick, HW v_exp_f32, key-split 8-wave); O-proj GEMM.

typedef __bf16 bf16_t;
typedef bf16_t bf16x8 __attribute__((ext_vector_type(8)));
typedef bf16_t bf16x4 __attribute__((ext_vector_type(4)));
typedef short  s16x4 __attribute__((ext_vector_type(4)));
typedef float  f32x4 __attribute__((ext_vector_type(4)));

#define SCALE_LOG2E 0.18033688011112042f  /* 0.125 * log2(e) */

__device__ __forceinline__ void async16(const bf16_t* g, void* l) {
    __builtin_amdgcn_global_load_lds(
        (const __attribute__((address_space(1))) unsigned int*)g,
        (__attribute__((address_space(3))) unsigned int*)l,
        16, 0, 0);
}

// ---------- cast fp32 -> bf16, 8 elems/thread ----------
__global__ __launch_bounds__(256) void cast_f32_bf16(
    const float* __restrict__ in, bf16_t* __restrict__ out, int n8)
{
    int i = blockIdx.x * 256 + threadIdx.x;
    if (i >= n8) return;
    const float4* p = (const float4*)in + (size_t)i * 2;
    float4 a = p[0], b = p[1];
    bf16x8 o;
    o[0] = (bf16_t)a.x; o[1] = (bf16_t)a.y; o[2] = (bf16_t)a.z; o[3] = (bf16_t)a.w;
    o[4] = (bf16_t)b.x; o[5] = (bf16_t)b.y; o[6] = (bf16_t)b.z; o[7] = (bf16_t)b.w;
    *((bf16x8*)out + i) = o;
}

// ---------- transpose + cast: W [1024][1024] fp32 [K][N] -> [N][K] bf16 ----------
__global__ __launch_bounds__(256) void transpose_cast(
    const float* __restrict__ W0, const float* __restrict__ W1,
    const float* __restrict__ W2, const float* __restrict__ W3,
    bf16_t* __restrict__ out)
{
    __shared__ float st[32][33];
    const float* W = (blockIdx.z == 0) ? W0 : (blockIdx.z == 1) ? W1
                   : (blockIdx.z == 2) ? W2 : W3;
    bf16_t* o = out + (size_t)blockIdx.z * 1024 * 1024;
    const int n0 = blockIdx.x * 32, k0 = blockIdx.y * 32;
    const int t = threadIdx.x;
    const int r = t >> 3, c4 = (t & 7) * 4;
    float4 v = *(const float4*)(W + (size_t)(k0 + r) * 1024 + n0 + c4);
    st[r][c4 + 0] = v.x; st[r][c4 + 1] = v.y; st[r][c4 + 2] = v.z; st[r][c4 + 3] = v.w;
    __syncthreads();
    bf16_t tmp[4] __attribute__((aligned(8)));
    #pragma unroll
    for (int i = 0; i < 4; ++i) tmp[i] = (bf16_t)st[c4 + i][r];
    *(uint2*)(o + (size_t)(n0 + r) * 1024 + k0 + c4) = *(const uint2*)tmp;
}

// ---------- MFMA GEMM: C = A[M,1024] @ Bt[N,1024]^T + bias ----------
// BK=64 (r9, -3us): two 32-wide slabs per LDS buffer staged/computed
// together -> 32 barrier-drains per block instead of 64. LDS 32KB (MT=128),
// 3 blocks/CU, occupancy unchanged.
template<bool FUSED, int MT>
__global__ __launch_bounds__(256, 3) void gemm_glds(
    const bf16_t* __restrict__ A, const bf16_t* __restrict__ Bt,
    const float* __restrict__ b0, const float* __restrict__ b1,
    const float* __restrict__ b2,
    bf16_t* __restrict__ Qo, bf16_t* __restrict__ Ko, bf16_t* __restrict__ Vo,
    float* __restrict__ Fo)
{
    const int K = 1024;
    __shared__ __align__(16) bf16_t As[2 * MT * 32];
    __shared__ __align__(16) bf16_t Bs[2 * 128 * 32];

    constexpr int NTPW = (MT == 128) ? 4 : 2;
    constexpr int JA   = MT / 64;

    const int tid  = threadIdx.x;
    const int wave = tid >> 6;
    const int lane = tid & 63;
    const int quad = lane >> 4;
    const int l16  = lane & 15;
    const int m0 = blockIdx.y * MT;
    const int n0 = blockIdx.x * 128;
    const int wm = (MT == 128) ? (wave >> 1) * 64 : 0;
    const int wn = (MT == 128) ? (wave & 1) * 64 : wave * 32;

    int goffA[JA], goffB[2];
    #pragma unroll
    for (int j = 0; j < JA; ++j) {
        const int row = j * 64 + (tid >> 2);
        const int cl  = (tid & 3) ^ ((row >> 1) & 3);
        goffA[j] = (m0 + row) * K + cl * 8;
    }
    #pragma unroll
    for (int j = 0; j < 2; ++j) {
        const int row = j * 64 + (tid >> 2);
        const int cl  = (tid & 3) ^ ((row >> 1) & 3);
        goffB[j] = (n0 + row) * K + cl * 8;
    }
    const int ldsoff = wave * 1024;

    f32x4 acc[4][NTPW] = {};
    const int sw = (l16 >> 1) & 3;

    for (int k0 = 0; k0 < K; k0 += 64) {
        #pragma unroll
        for (int s = 0; s < 2; ++s) {
            #pragma unroll
            for (int j = 0; j < JA; ++j)
                async16(A + goffA[j] + k0 + s * 32,
                        (char*)As + s * (MT * 64) + j * 4096 + ldsoff);
            #pragma unroll
            for (int j = 0; j < 2; ++j)
                async16(Bt + goffB[j] + k0 + s * 32,
                        (char*)Bs + s * 8192 + j * 4096 + ldsoff);
        }
        __syncthreads();

        #pragma unroll
        for (int s = 0; s < 2; ++s) {
            bf16x8 af[4], bfr[NTPW];
            #pragma unroll
            for (int mt = 0; mt < 4; ++mt)
                af[mt] = *(const bf16x8*)(&As[s * (MT * 32) +
                    (wm + mt * 16 + l16) * 32 + (quad ^ sw) * 8]);
            #pragma unroll
            for (int nt = 0; nt < NTPW; ++nt)
                bfr[nt] = *(const bf16x8*)(&Bs[s * (128 * 32) +
                    (wn + nt * 16 + l16) * 32 + (quad ^ sw) * 8]);
            #pragma unroll
            for (int mt = 0; mt < 4; ++mt)
                #pragma unroll
                for (int nt = 0; nt < NTPW; ++nt)
                    acc[mt][nt] = __builtin_amdgcn_mfma_f32_16x16x32_bf16(
                        af[mt], bfr[nt], acc[mt][nt], 0, 0, 0);
        }
        __syncthreads();
    }

    if (FUSED) {
        const int sel = n0 >> 10;
        const float* bias = (sel == 0) ? b0 : (sel == 1) ? b1 : b2;
        bf16_t* Cout      = (sel == 0) ? Qo : (sel == 1) ? Ko : Vo;
        const float scl   = (sel == 1) ? SCALE_LOG2E : 1.0f;
        const int nb = n0 & 1023;
        #pragma unroll
        for (int nt = 0; nt < NTPW; ++nt) {
            const int n = nb + wn + nt * 16 + l16;
            const float bb = bias[n];
            #pragma unroll
            for (int mt = 0; mt < 4; ++mt)
                #pragma unroll
                for (int i = 0; i < 4; ++i) {
                    const int m = m0 + wm + mt * 16 + quad * 4 + i;
                    Cout[(size_t)m * 1024 + n] = (bf16_t)((acc[mt][nt][i] + bb) * scl);
                }
        }
    } else {
        #pragma unroll
        for (int nt = 0; nt < NTPW; ++nt) {
            const int n = n0 + wn + nt * 16 + l16;
            const float bb = b0[n];
            #pragma unroll
            for (int mt = 0; mt < 4; ++mt)
                #pragma unroll
                for (int i = 0; i < 4; ++i) {
                    const int m = m0 + wm + mt * 16 + quad * 4 + i;
                    Fo[(size_t)m * 1024 + n] = acc[mt][nt][i] + bb;
                }
        }
    }
}

// ---------- MFMA flash attention, key-split 8-wave ----------
// Structure unchanged from r8/r9 (proven 53.9us): grid 1024, 512 thr =
// 8 waves; waves 0-3 key tiles 0-7, waves 4-7 key tiles 8-15 (same q rows);
// additive partial combine via LDS; full-head V^T staged once; barrier-free
// main loop; kfA/kfB named K dbuf.
// THIS ROUND'S ONE CHANGE: exp->pack via four plain (bf16_t) casts into an
// ext_vector bf16x4 — LLVM pattern-matches adjacent f32->bf16 casts into
// v_cvt_pk_bf16_f32 WITH correct TRANS-hazard handling (learn_hip m240:
// compiler cast beats inline-asm cvt_pk). Replaces 4x +0x8000 add + 2x
// v_perm (6 VALU per 4 scores -> 2). Rounding: RNE vs round-half-up, both
// well inside threshold.
// LEDGER CLOSED r10: inline-asm v_cvt_pk_bf16_f32 after v_exp_f32 => NaN
// (TRANS->asm consumer gets no hazard wait-states). NEVER hand-write it.
// _1k-QK exonerated (r6 abort was a sick node); retryable later.
// Other ledger: r3 reg-cap spill; r4 q-split FETCH x2; r5 asm barrier
// fractured sched; r7 barrier-free -2us; r8 key-split -1.5us; r9 BK=64 -3us.
__global__ __launch_bounds__(512, 4) void attn_kernel(
    const bf16_t* __restrict__ Q, const bf16_t* __restrict__ K,
    const bf16_t* __restrict__ V, bf16_t* __restrict__ Z)
{
    __shared__ __align__(16) char smem[16 * 1032 * 2];
    bf16_t (*Vt)[1032] = (bf16_t (*)[1032])smem;
    float* cmb = (float*)smem;     // [4 waves][64 lanes][21]

    const int tid  = threadIdx.x;
    const int wave = tid >> 6;        // 0..7
    const int lane = tid & 63;
    const int quad = lane >> 4;
    const int l16  = lane & 15;
    const int hd = blockIdx.x >> 2;
    const int qc = blockIdx.x & 3;
    const int a = hd >> 2, b = hd & 3;
    const int col0 = a * 16;
    const int qw   = wave & 3;
    const int kvh  = wave >> 2;
    const int qbase = qc * 256 + qw * 64;
    const int kb512 = kvh * 512;

    const int r  = tid >> 2;
    const int dq = (tid & 3) * 4;
    const bf16_t* Vp = V + (size_t)(b * 1024 + r) * 1024 + col0 + dq;
    #pragma unroll 2
    for (int t = 0; t < 8; ++t) {
        uint2 vv = *(const uint2*)(Vp + (size_t)(t * 128) * 1024);
        bf16_t t4[4] __attribute__((aligned(8)));
        *(uint2*)t4 = vv;
        #pragma unroll
        for (int ii = 0; ii < 4; ++ii)
            Vt[dq + ii][t * 128 + r] = t4[ii];
    }

    bf16x8 qf[4] = {};
    if (quad < 2) {
        #pragma unroll
        for (int qs = 0; qs < 4; ++qs)
            qf[qs] = *(const bf16x8*)(Q +
                (size_t)(b * 1024 + qbase + qs * 16 + l16) * 1024 + col0 + quad * 8);
    }

    const bf16_t* Kp = K + (size_t)(b * 1024 + kb512 + l16) * 1024 + col0 + quad * 8;
    bf16x8 kfA[4] = {}, kfB[4] = {};
    if (quad < 2) {
        #pragma unroll
        for (int kt = 0; kt < 4; ++kt)
            kfA[kt] = *(const bf16x8*)(Kp + (size_t)(kt * 16) * 1024);
    }

    __syncthreads();   // Vt ready

    const s16x4 ones = { 0x3F80, 0x3F80, 0x3F80, 0x3F80 };  // bf16 1.0 x4

    f32x4 zacc[4] = {};
    f32x4 lacc[4] = {};

#define ATTN_TILE(JIDX, KFCUR, KFNXT, DO_PREFETCH)                            \
    {                                                                         \
        const int j_ = (JIDX);                                                \
        if (DO_PREFETCH && quad < 2) {                                        \
            _Pragma("unroll")                                                 \
            for (int kt = 0; kt < 4; ++kt)                                    \
                KFNXT[kt] = *(const bf16x8*)(                                 \
                    Kp + (size_t)((j_ + 1) * 64 + kt * 16) * 1024);           \
        }                                                                     \
        _Pragma("unroll")                                                     \
        for (int kt = 0; kt < 4; ++kt) {                                      \
            const s16x4 vfrag = __builtin_bit_cast(s16x4,                     \
                *(const uint2*)(&Vt[l16][kb512 + j_ * 64 + kt * 16 + quad * 4])); \
            _Pragma("unroll")                                                 \
            for (int qs = 0; qs < 4; ++qs) {                                  \
                f32x4 zc = {0.f, 0.f, 0.f, 0.f};                              \
                f32x4 s = __builtin_amdgcn_mfma_f32_16x16x32_bf16(            \
                    KFCUR[kt], qf[qs], zc, 0, 0, 0);                          \
                const float e0 = __builtin_amdgcn_exp2f(s[0]);                \
                const float e1 = __builtin_amdgcn_exp2f(s[1]);                \
                const float e2 = __builtin_amdgcn_exp2f(s[2]);                \
                const float e3 = __builtin_amdgcn_exp2f(s[3]);                \
                bf16x4 pv;                                                    \
                pv[0] = (bf16_t)e0; pv[1] = (bf16_t)e1;                       \
                pv[2] = (bf16_t)e2; pv[3] = (bf16_t)e3;                       \
                const s16x4 pfrag = __builtin_bit_cast(s16x4, pv);            \
                zacc[qs] = __builtin_amdgcn_mfma_f32_16x16x16bf16_1k(         \
                    vfrag, pfrag, zacc[qs], 0, 0, 0);                         \
                lacc[qs] = __builtin_amdgcn_mfma_f32_16x16x16bf16_1k(         \
                    ones, pfrag, lacc[qs], 0, 0, 0);                          \
            }                                                                 \
        }                                                                     \
    }

    #pragma unroll 1
    for (int j2 = 0; j2 < 4; ++j2) {
        ATTN_TILE(2 * j2,     kfA, kfB, true)
        ATTN_TILE(2 * j2 + 1, kfB, kfA, (j2 < 3))
    }
#undef ATTN_TILE

    __syncthreads();
    if (wave >= 4) {
        float* p = cmb + ((size_t)((wave - 4) * 64 + lane)) * 21;
        #pragma unroll
        for (int qs = 0; qs < 4; ++qs) {
            #pragma unroll
            for (int i = 0; i < 4; ++i) p[qs * 4 + i] = zacc[qs][i];
            p[16 + qs] = lacc[qs][0];
        }
    }
    __syncthreads();
    if (wave < 4) {
        const float* p = cmb + ((size_t)(wave * 64 + lane)) * 21;
        #pragma unroll
        for (int qs = 0; qs < 4; ++qs) {
            const float inv = 1.0f / (lacc[qs][0] + p[16 + qs]);
            const int q = qbase + qs * 16 + l16;
            bf16_t o4[4] __attribute__((aligned(8)));
            #pragma unroll
            for (int i = 0; i < 4; ++i)
                o4[i] = (bf16_t)((zacc[qs][i] + p[qs * 4 + i]) * inv);
            *(uint2*)(Z + ((size_t)hd * 1024 + q) * 16 + quad * 4) = *(const uint2*)o4;
        }
    }
}

extern "C" void kernel_launch(void* const* d_in, const int* in_sizes, int n_in,
                              void* d_out, int out_size, void* d_ws, size_t ws_size,
                              hipStream_t stream) {
    const float* x  = (const float*)d_in[0];
    const float* Wq = (const float*)d_in[1];
    const float* bq = (const float*)d_in[2];
    const float* Wk = (const float*)d_in[3];
    const float* bk = (const float*)d_in[4];
    const float* Wv = (const float*)d_in[5];
    const float* bv = (const float*)d_in[6];
    const float* Wo = (const float*)d_in[7];
    const float* bo = (const float*)d_in[8];
    float* out = (float*)d_out;

    char* ws = (char*)d_ws;
    bf16_t* x_bf = (bf16_t*)(ws);
    bf16_t* Wt   = (bf16_t*)(ws + (8u << 20));   // q|k|v|o slabs, contiguous
    bf16_t* Qb   = (bf16_t*)(ws + (16u << 20));
    bf16_t* Kb   = (bf16_t*)(ws + (24u << 20));
    bf16_t* Vb   = (bf16_t*)(ws + (32u << 20));
    bf16_t* Zb   = (bf16_t*)(ws + (40u << 20));
    bf16_t* WtO  = Wt + (size_t)3 * 1024 * 1024;

    cast_f32_bf16<<<dim3(2048), dim3(256), 0, stream>>>(x, x_bf, 524288);
    transpose_cast<<<dim3(32, 32, 4), dim3(256), 0, stream>>>(Wq, Wk, Wv, Wo, Wt);

    // fused QKV: Bt = [3072][1024] (Wq|Wk|Wv)
    gemm_glds<true, 128><<<dim3(24, 32), dim3(256), 0, stream>>>(
        x_bf, Wt, bq, bk, bv, Qb, Kb, Vb, nullptr);

    attn_kernel<<<dim3(1024), dim3(512), 0, stream>>>(Qb, Kb, Vb, Zb);

    // O-projection: 64x128 tiles -> 512 blocks (2/CU)
    gemm_glds<false, 64><<<dim3(8, 64), dim3(256), 0, stream>>>(
        Zb, WtO, bo, nullptr, nullptr, nullptr, nullptr, nullptr, out);
}